// Round 1
// baseline (5730.542 us; speedup 1.0000x reference)
//
#include <hip/hip_runtime.h>
#include <math.h>

// Problem constants
#define LDIM 8192   // H*W = 16*512
#define NC   512
#define NM   1024

static constexpr float kEps        = 1e-4f;
static constexpr float kInvSqrt512 = 0.044194173824159216f;  // 1/sqrt(512)
static constexpr float kInvSqrt1024= 0.03125f;               // 1/sqrt(1024)
static constexpr float kInvSqrt1152= 0.029462782549439483f;  // 1/sqrt(128*9)
static constexpr float kQScale     = 0.08838834764831845f;   // 1/sqrt(128)
static constexpr float kInvSqrt2   = 0.7071067811865476f;
static constexpr float kInvSilu    = 1.0f / 0.596f;

// ---------------------------------------------------------------------------
// Pixel norm over channels: xn[c,l] = x[c,l] / (eps + sqrt(mean_c x^2))
__global__ void k_norm_x(const float* __restrict__ x, float* __restrict__ xn) {
    int l = blockIdx.x * 256 + threadIdx.x;
    float ss = 0.f;
    for (int c = 0; c < NC; ++c) { float v = x[(size_t)c * LDIM + l]; ss += v * v; }
    float rn = 1.f / (kEps + sqrtf(ss * (1.0f / 512.0f)));
    for (int c = 0; c < NC; ++c) xn[(size_t)c * LDIM + l] = x[(size_t)c * LDIM + l] * rn;
}

// ---------------------------------------------------------------------------
// cvec[m] = emb_gain/sqrt(512) * sum_e w_emb[m,e]*emb[e] + 1   (one wave/row)
__global__ void k_emb(const float* __restrict__ w_emb, const float* __restrict__ emb,
                      const float* __restrict__ eg, float* __restrict__ cvec) {
    int wave = threadIdx.x >> 6, lane = threadIdx.x & 63;
    int m = blockIdx.x * 4 + wave;
    float s = 0.f;
    for (int e = lane; e < 512; e += 64) s += w_emb[(size_t)m * 512 + e] * emb[e];
    for (int off = 32; off; off >>= 1) s += __shfl_down(s, off);
    if (lane == 0) cvec[m] = eg[0] * kInvSqrt512 * s + 1.0f;
}

// ---------------------------------------------------------------------------
// fp32 GEMM: out[m,l] = scale * sum_k A[m,k]*B[k,l];  L fixed = 8192.
// 64x64 block tile, 16 k-slice, 4x4 micro-tile per thread (256 threads).
__launch_bounds__(256)
__global__ void k_gemm(const float* __restrict__ A, const float* __restrict__ B,
                       float* __restrict__ Cout, int K, float scale) {
    __shared__ float As[16][68];   // [k][m], padded
    __shared__ float Bs[16][64];   // [k][l]
    int t = threadIdx.x;
    int tn = t & 15, tm = t >> 4;
    int l0 = blockIdx.x * 64, m0 = blockIdx.y * 64;
    float acc[4][4] = {};
    for (int k0 = 0; k0 < K; k0 += 16) {
        {
            int row = t >> 2, col = (t & 3) * 4;
            float4 av = *(const float4*)(A + (size_t)(m0 + row) * K + k0 + col);
            As[col + 0][row] = av.x; As[col + 1][row] = av.y;
            As[col + 2][row] = av.z; As[col + 3][row] = av.w;
            int brow = t >> 4, bcol = (t & 15) * 4;
            float4 bv = *(const float4*)(B + (size_t)(k0 + brow) * LDIM + l0 + bcol);
            *(float4*)&Bs[brow][bcol] = bv;
        }
        __syncthreads();
        #pragma unroll
        for (int kk = 0; kk < 16; ++kk) {
            float a[4], b[4];
            *(float4*)a = *(const float4*)&As[kk][tm * 4];
            *(float4*)b = *(const float4*)&Bs[kk][tn * 4];
            #pragma unroll
            for (int i = 0; i < 4; ++i)
                #pragma unroll
                for (int j = 0; j < 4; ++j)
                    acc[i][j] = fmaf(a[i], b[j], acc[i][j]);
        }
        __syncthreads();
    }
    #pragma unroll
    for (int i = 0; i < 4; ++i) {
        float4 o;
        o.x = acc[i][0] * scale; o.y = acc[i][1] * scale;
        o.z = acc[i][2] * scale; o.w = acc[i][3] * scale;
        *(float4*)&Cout[(size_t)(m0 + tm * 4 + i) * LDIM + l0 + tn * 4] = o;
    }
}

// ---------------------------------------------------------------------------
// Grouped 1x9 conv along W (+ per-channel gate + mp_silu epilogue).
// grid: (m-tile of 16, h). block 128 threads, thread owns 4 w positions.
__launch_bounds__(128)
__global__ void k_gconv(const float* __restrict__ y1, const float* __restrict__ wd,
                        const float* __restrict__ cvec, float* __restrict__ y2) {
    __shared__ float in_s[8][520];      // 8 channels x (512 + 2*4) padded W
    __shared__ float w_s[16][8][9];     // [mm][ci][tap]
    int t = threadIdx.x;
    int m0 = blockIdx.x * 16;
    int h  = blockIdx.y;
    int g  = m0 >> 7;                   // group (128 channels per group)
    float acc[16][4] = {};
    for (int cc = 0; cc < 16; ++cc) {   // 16 chunks of 8 input channels
        __syncthreads();
        for (int idx = t; idx < 8 * 520; idx += 128) {
            int ci = idx / 520, ww = idx - ci * 520;
            int w = ww - 4;
            float v = 0.f;
            if (w >= 0 && w < 512)
                v = y1[(size_t)(g * 128 + cc * 8 + ci) * LDIM + h * 512 + w];
            in_s[ci][ww] = v;
        }
        for (int idx = t; idx < 16 * 8 * 9; idx += 128) {
            int mm = idx / 72, r = idx - mm * 72;
            int ci = r / 9, tap = r - ci * 9;
            w_s[mm][ci][tap] = wd[((size_t)(m0 + mm) * 128 + cc * 8 + ci) * 9 + tap];
        }
        __syncthreads();
        for (int ci = 0; ci < 8; ++ci) {
            float win[12];
            *(float4*)&win[0] = *(const float4*)&in_s[ci][t * 4];
            *(float4*)&win[4] = *(const float4*)&in_s[ci][t * 4 + 4];
            *(float4*)&win[8] = *(const float4*)&in_s[ci][t * 4 + 8];
            #pragma unroll
            for (int mm = 0; mm < 16; ++mm)
                #pragma unroll
                for (int tap = 0; tap < 9; ++tap) {
                    float wv = w_s[mm][ci][tap];
                    #pragma unroll
                    for (int o = 0; o < 4; ++o)
                        acc[mm][o] = fmaf(wv, win[tap + o], acc[mm][o]);
                }
        }
    }
    #pragma unroll
    for (int mm = 0; mm < 16; ++mm) {
        float cv = cvec[m0 + mm];
        #pragma unroll
        for (int o = 0; o < 4; ++o) {
            float z = acc[mm][o] * kInvSqrt1152 * cv;
            float sig = 1.0f / (1.0f + __expf(-z));
            y2[(size_t)(m0 + mm) * LDIM + h * 512 + t * 4 + o] = z * sig * kInvSilu;
        }
    }
}

// ---------------------------------------------------------------------------
__global__ void k_mpsum(const float* __restrict__ a, const float* __restrict__ b,
                        float* __restrict__ out) {
    size_t i = (size_t)blockIdx.x * 256 + threadIdx.x;
    out[i] = (a[i] + b[i]) * kInvSqrt2;
}

// pe[2c, l] = xs[c,l] ; pe[2c+1, l] = xs[c,l]*pos[c,l]
__global__ void k_pe(const float* __restrict__ xs, const float* __restrict__ pos,
                     float* __restrict__ pe) {
    size_t i = (size_t)blockIdx.x * 256 + threadIdx.x;   // i = c*L + l
    size_t c = i >> 13, l = i & 8191;
    float v = xs[i];
    pe[(2 * c) * LDIM + l]     = v;
    pe[(2 * c + 1) * LDIM + l] = v * pos[i];
}

// normalize qk over d (128) for each (head, q/k, token); channel m=(h*128+dd)*2+s
__global__ void k_norm_qk(float* __restrict__ qk) {
    int l = blockIdx.x * 256 + threadIdx.x;
    for (int hs = 0; hs < 8; ++hs) {
        int h = hs >> 1, s = hs & 1;
        size_t base = ((size_t)(h * 256 + s)) * LDIM + l;
        float ss = 0.f;
        for (int dd = 0; dd < 128; ++dd) {
            float v = qk[base + (size_t)dd * 2 * LDIM]; ss += v * v;
        }
        float rn = 1.f / (kEps + sqrtf(ss * (1.0f / 128.0f)));
        for (int dd = 0; dd < 128; ++dd) qk[base + (size_t)dd * 2 * LDIM] *= rn;
    }
}

__global__ void k_norm_v(float* __restrict__ v) {
    int l = blockIdx.x * 256 + threadIdx.x;
    for (int h = 0; h < 4; ++h) {
        size_t base = (size_t)h * 128 * LDIM + l;
        float ss = 0.f;
        for (int dd = 0; dd < 128; ++dd) {
            float t = v[base + (size_t)dd * LDIM]; ss += t * t;
        }
        float rn = 1.f / (kEps + sqrtf(ss * (1.0f / 128.0f)));
        for (int dd = 0; dd < 128; ++dd) v[base + (size_t)dd * LDIM] *= rn;
    }
}

// ---------------------------------------------------------------------------
// Flash attention fp32 + final residual + clip.
// grid: (L/64 q-tiles, 4 heads). 256 threads. TQ=64, TK=16.
// Thread roles: S-phase (tm=t>>4 rows*4, tn=t&15 one col);
// softmax/O-phase: row r=t>>2 owned by 4 lanes q=t&3 (same wave as S rows).
__launch_bounds__(256)
__global__ void k_attn(const float* __restrict__ qk, const float* __restrict__ v,
                       const float* __restrict__ xs, float* __restrict__ out) {
    __shared__ float Qs[128][64];   // [d][r], pre-scaled by 1/sqrt(128)
    __shared__ float Ks[128][16];   // [d][j]
    __shared__ float Vs[128][16];   // [d][j]
    __shared__ float Ss[64][20];    // [r][j] scores -> probabilities
    int t = threadIdx.x;
    int i0 = blockIdx.x * 64;
    int h  = blockIdx.y;

    for (int idx = t; idx < 128 * 64; idx += 256) {
        int dd = idx >> 6, r = idx & 63;
        Qs[dd][r] = qk[((size_t)(h * 128 + dd) * 2) * LDIM + i0 + r] * kQScale;
    }

    int r = t >> 2, q = t & 3;
    int tn = t & 15, tm = t >> 4;
    float o[32] = {};
    float mrun = -1e30f, lrun = 0.f;

    for (int j0 = 0; j0 < LDIM; j0 += 16) {
        __syncthreads();   // safe to overwrite K/V
        for (int idx = t; idx < 128 * 16; idx += 256) {
            int dd = idx >> 4, j = idx & 15;
            Ks[dd][j] = qk[(((size_t)(h * 128 + dd) * 2) + 1) * LDIM + j0 + j];
            Vs[dd][j] = v[((size_t)(h * 128 + dd)) * LDIM + j0 + j];
        }
        __syncthreads();

        // S = (Q/sqrt(d))^T K : rows tm*4..tm*4+3, col tn
        float acc[4] = {};
        for (int dd = 0; dd < 128; ++dd) {
            float4 a = *(const float4*)&Qs[dd][tm * 4];
            float b = Ks[dd][tn];
            acc[0] = fmaf(a.x, b, acc[0]);
            acc[1] = fmaf(a.y, b, acc[1]);
            acc[2] = fmaf(a.z, b, acc[2]);
            acc[3] = fmaf(a.w, b, acc[3]);
        }
        #pragma unroll
        for (int i = 0; i < 4; ++i) Ss[tm * 4 + i][tn] = acc[i];
        __syncthreads();

        // online softmax: row r, this thread covers cols q*4..q*4+3
        float mloc = -1e30f;
        #pragma unroll
        for (int jj = 0; jj < 4; ++jj) mloc = fmaxf(mloc, Ss[r][q * 4 + jj]);
        mloc = fmaxf(mloc, __shfl_xor(mloc, 1));
        mloc = fmaxf(mloc, __shfl_xor(mloc, 2));
        float mnew = fmaxf(mrun, mloc);
        float alpha = __expf(mrun - mnew);
        float lloc = 0.f;
        #pragma unroll
        for (int jj = 0; jj < 4; ++jj) {
            float p = __expf(Ss[r][q * 4 + jj] - mnew);
            Ss[r][q * 4 + jj] = p;
            lloc += p;
        }
        lloc += __shfl_xor(lloc, 1);
        lloc += __shfl_xor(lloc, 2);
        lrun = lrun * alpha + lloc;
        mrun = mnew;
        #pragma unroll
        for (int dl = 0; dl < 32; ++dl) o[dl] *= alpha;
        __syncthreads();

        // O[r][d] += sum_j P[r][j] * V[d][j];  thread owns d = q + 4*dl
        #pragma unroll
        for (int jj = 0; jj < 4; ++jj) {
            float4 p4 = *(const float4*)&Ss[r][jj * 4];
            #pragma unroll
            for (int dl = 0; dl < 32; ++dl) {
                float4 v4 = *(const float4*)&Vs[q + 4 * dl][jj * 4];
                o[dl] += p4.x * v4.x + p4.y * v4.y + p4.z * v4.z + p4.w * v4.w;
            }
        }
    }

    float rl = 1.f / lrun;
    #pragma unroll
    for (int dl = 0; dl < 32; ++dl) {
        int c = h * 128 + q + 4 * dl;
        size_t gi = (size_t)c * LDIM + i0 + r;
        float val = (xs[gi] + o[dl] * rl) * kInvSqrt2;
        val = fminf(fmaxf(val, -256.f), 256.f);
        out[gi] = val;
    }
}

// ---------------------------------------------------------------------------
extern "C" void kernel_launch(void* const* d_in, const int* in_sizes, int n_in,
                              void* d_out, int out_size, void* d_ws, size_t ws_size,
                              hipStream_t stream) {
    const float* x      = (const float*)d_in[0];
    const float* emb    = (const float*)d_in[1];
    const float* pos    = (const float*)d_in[2];
    const float* eg     = (const float*)d_in[3];
    const float* w_res0 = (const float*)d_in[4];
    const float* w_depth= (const float*)d_in[5];
    const float* w_emb  = (const float*)d_in[6];
    const float* w_res1 = (const float*)d_in[7];
    const float* w_qk   = (const float*)d_in[8];
    const float* w_v    = (const float*)d_in[9];
    float* out = (float*)d_out;

    float* W  = (float*)d_ws;
    float* xn = W;                                   // 4M floats: xn -> xs (in place)
    float* B1 = W + (size_t)4  * 1024 * 1024;        // 8M floats: y1 -> y3 -> qk
    float* B2 = W + (size_t)12 * 1024 * 1024;        // 8M floats: y2 -> pe -> v
    float* cv = W + (size_t)20 * 1024 * 1024;        // 1024 floats

    k_norm_x<<<32, 256, 0, stream>>>(x, xn);
    k_emb<<<256, 256, 0, stream>>>(w_emb, emb, eg, cv);
    // y1 = res0(xn): M=1024, K=512
    k_gemm<<<dim3(128, 16), 256, 0, stream>>>(w_res0, xn, B1, 512, kInvSqrt512);
    // y2 = silu(gconv(y1) * c)
    k_gconv<<<dim3(64, 16), 128, 0, stream>>>(B1, w_depth, cv, B2);
    // y3 = res1(y2): M=512, K=1024 -> into B1 (y1 dead)
    k_gemm<<<dim3(128, 8), 256, 0, stream>>>(w_res1, B2, B1, 1024, kInvSqrt1024);
    // xs = (xn + y3)/sqrt(2), in place over xn
    k_mpsum<<<16384, 256, 0, stream>>>(xn, B1, xn);
    // pe -> B2 (y2 dead)
    k_pe<<<16384, 256, 0, stream>>>(xn, pos, B2);
    // qk = w_qk @ pe: M=1024, K=1024 -> B1
    k_gemm<<<dim3(128, 16), 256, 0, stream>>>(w_qk, B2, B1, 1024, kInvSqrt1024);
    k_norm_qk<<<32, 256, 0, stream>>>(B1);
    // v = w_v @ xs: M=512, K=512 -> B2 (pe dead)
    k_gemm<<<dim3(128, 8), 256, 0, stream>>>(w_v, xn, B2, 512, kInvSqrt512);
    k_norm_v<<<32, 256, 0, stream>>>(B2);
    // attention + residual + clip -> out
    k_attn<<<dim3(128, 4), 256, 0, stream>>>(B1, B2, xn, out);
}

// Round 2
// 1893.025 us; speedup vs baseline: 3.0272x; 3.0272x over previous
//
#include <hip/hip_runtime.h>
#include <math.h>

// Problem constants
#define LDIM 8192   // H*W = 16*512
#define NC   512
#define NM   1024

typedef unsigned short u16;
typedef short bf16x8 __attribute__((ext_vector_type(8)));
typedef float f32x4  __attribute__((ext_vector_type(4)));

static constexpr float kEps        = 1e-4f;
static constexpr float kInvSqrt512 = 0.044194173824159216f;  // 1/sqrt(512)
static constexpr float kInvSqrt1024= 0.03125f;               // 1/sqrt(1024)
static constexpr float kInvSqrt1152= 0.029462782549439483f;  // 1/sqrt(128*9)
static constexpr float kQScale     = 0.08838834764831845f;   // 1/sqrt(128)
static constexpr float kInvSqrt2   = 0.7071067811865476f;
static constexpr float kInvSilu    = 1.0f / 0.596f;

__device__ __forceinline__ u16 f2bf(float f) {
    unsigned int u = __float_as_uint(f);
    u += 0x7fff + ((u >> 16) & 1);   // round-to-nearest-even
    return (u16)(u >> 16);
}

// ---------------------------------------------------------------------------
// Pixel norm over channels: xn[c,l] = x[c,l] / (eps + sqrt(mean_c x^2))
__global__ void k_norm_x(const float* __restrict__ x, float* __restrict__ xn) {
    int l = blockIdx.x * 256 + threadIdx.x;
    float ss = 0.f;
    for (int c = 0; c < NC; ++c) { float v = x[(size_t)c * LDIM + l]; ss += v * v; }
    float rn = 1.f / (kEps + sqrtf(ss * (1.0f / 512.0f)));
    for (int c = 0; c < NC; ++c) xn[(size_t)c * LDIM + l] = x[(size_t)c * LDIM + l] * rn;
}

// ---------------------------------------------------------------------------
// cvec[m] = emb_gain/sqrt(512) * sum_e w_emb[m,e]*emb[e] + 1   (one wave/row)
__global__ void k_emb(const float* __restrict__ w_emb, const float* __restrict__ emb,
                      const float* __restrict__ eg, float* __restrict__ cvec) {
    int wave = threadIdx.x >> 6, lane = threadIdx.x & 63;
    int m = blockIdx.x * 4 + wave;
    float s = 0.f;
    for (int e = lane; e < 512; e += 64) s += w_emb[(size_t)m * 512 + e] * emb[e];
    for (int off = 32; off; off >>= 1) s += __shfl_down(s, off);
    if (lane == 0) cvec[m] = eg[0] * kInvSqrt512 * s + 1.0f;
}

// ---------------------------------------------------------------------------
// fp32 GEMM: out[m,l] = scale * sum_k A[m,k]*B[k,l];  L fixed = 8192.
__launch_bounds__(256)
__global__ void k_gemm(const float* __restrict__ A, const float* __restrict__ B,
                       float* __restrict__ Cout, int K, float scale) {
    __shared__ float As[16][68];
    __shared__ float Bs[16][64];
    int t = threadIdx.x;
    int tn = t & 15, tm = t >> 4;
    int l0 = blockIdx.x * 64, m0 = blockIdx.y * 64;
    float acc[4][4] = {};
    for (int k0 = 0; k0 < K; k0 += 16) {
        {
            int row = t >> 2, col = (t & 3) * 4;
            float4 av = *(const float4*)(A + (size_t)(m0 + row) * K + k0 + col);
            As[col + 0][row] = av.x; As[col + 1][row] = av.y;
            As[col + 2][row] = av.z; As[col + 3][row] = av.w;
            int brow = t >> 4, bcol = (t & 15) * 4;
            float4 bv = *(const float4*)(B + (size_t)(k0 + brow) * LDIM + l0 + bcol);
            *(float4*)&Bs[brow][bcol] = bv;
        }
        __syncthreads();
        #pragma unroll
        for (int kk = 0; kk < 16; ++kk) {
            float a[4], b[4];
            *(float4*)a = *(const float4*)&As[kk][tm * 4];
            *(float4*)b = *(const float4*)&Bs[kk][tn * 4];
            #pragma unroll
            for (int i = 0; i < 4; ++i)
                #pragma unroll
                for (int j = 0; j < 4; ++j)
                    acc[i][j] = fmaf(a[i], b[j], acc[i][j]);
        }
        __syncthreads();
    }
    #pragma unroll
    for (int i = 0; i < 4; ++i) {
        float4 o;
        o.x = acc[i][0] * scale; o.y = acc[i][1] * scale;
        o.z = acc[i][2] * scale; o.w = acc[i][3] * scale;
        *(float4*)&Cout[(size_t)(m0 + tm * 4 + i) * LDIM + l0 + tn * 4] = o;
    }
}

// ---------------------------------------------------------------------------
// Grouped 1x9 conv along W (+ per-channel gate + mp_silu epilogue).
__launch_bounds__(128)
__global__ void k_gconv(const float* __restrict__ y1, const float* __restrict__ wd,
                        const float* __restrict__ cvec, float* __restrict__ y2) {
    __shared__ float in_s[8][520];
    __shared__ float w_s[16][8][9];
    int t = threadIdx.x;
    int m0 = blockIdx.x * 16;
    int h  = blockIdx.y;
    int g  = m0 >> 7;
    float acc[16][4] = {};
    for (int cc = 0; cc < 16; ++cc) {
        __syncthreads();
        for (int idx = t; idx < 8 * 520; idx += 128) {
            int ci = idx / 520, ww = idx - ci * 520;
            int w = ww - 4;
            float v = 0.f;
            if (w >= 0 && w < 512)
                v = y1[(size_t)(g * 128 + cc * 8 + ci) * LDIM + h * 512 + w];
            in_s[ci][ww] = v;
        }
        for (int idx = t; idx < 16 * 8 * 9; idx += 128) {
            int mm = idx / 72, r = idx - mm * 72;
            int ci = r / 9, tap = r - ci * 9;
            w_s[mm][ci][tap] = wd[((size_t)(m0 + mm) * 128 + cc * 8 + ci) * 9 + tap];
        }
        __syncthreads();
        for (int ci = 0; ci < 8; ++ci) {
            float win[12];
            *(float4*)&win[0] = *(const float4*)&in_s[ci][t * 4];
            *(float4*)&win[4] = *(const float4*)&in_s[ci][t * 4 + 4];
            *(float4*)&win[8] = *(const float4*)&in_s[ci][t * 4 + 8];
            #pragma unroll
            for (int mm = 0; mm < 16; ++mm)
                #pragma unroll
                for (int tap = 0; tap < 9; ++tap) {
                    float wv = w_s[mm][ci][tap];
                    #pragma unroll
                    for (int o = 0; o < 4; ++o)
                        acc[mm][o] = fmaf(wv, win[tap + o], acc[mm][o]);
                }
        }
    }
    #pragma unroll
    for (int mm = 0; mm < 16; ++mm) {
        float cv = cvec[m0 + mm];
        #pragma unroll
        for (int o = 0; o < 4; ++o) {
            float z = acc[mm][o] * kInvSqrt1152 * cv;
            float sig = 1.0f / (1.0f + __expf(-z));
            y2[(size_t)(m0 + mm) * LDIM + h * 512 + t * 4 + o] = z * sig * kInvSilu;
        }
    }
}

// ---------------------------------------------------------------------------
__global__ void k_mpsum(const float* __restrict__ a, const float* __restrict__ b,
                        float* __restrict__ out) {
    size_t i = (size_t)blockIdx.x * 256 + threadIdx.x;
    out[i] = (a[i] + b[i]) * kInvSqrt2;
}

__global__ void k_pe(const float* __restrict__ xs, const float* __restrict__ pos,
                     float* __restrict__ pe) {
    size_t i = (size_t)blockIdx.x * 256 + threadIdx.x;
    size_t c = i >> 13, l = i & 8191;
    float v = xs[i];
    pe[(2 * c) * LDIM + l]     = v;
    pe[(2 * c + 1) * LDIM + l] = v * pos[i];
}

// ---------------------------------------------------------------------------
// Normalize q,k over d and emit bf16 transposed [h][token][d]; q pre-scaled 1/sqrt(d).
__global__ void k_norm_qk_t(const float* __restrict__ qk, u16* __restrict__ q_t,
                            u16* __restrict__ k_t) {
    int l = blockIdx.x * 256 + threadIdx.x;
    for (int hs = 0; hs < 8; ++hs) {
        int h = hs >> 1, s = hs & 1;
        size_t base = ((size_t)(h * 256 + s)) * LDIM + l;
        float ss = 0.f;
        for (int dd = 0; dd < 128; ++dd) {
            float v = qk[base + (size_t)dd * 2 * LDIM];
            ss += v * v;
        }
        float rn = 1.f / (kEps + sqrtf(ss * (1.0f / 128.0f)));
        if (s == 0) rn *= kQScale;
        u16* dst = (s ? k_t : q_t) + ((size_t)h * LDIM + l) * 128;
        for (int dq = 0; dq < 16; ++dq) {
            u16 tmp[8];
            #pragma unroll
            for (int j = 0; j < 8; ++j)
                tmp[j] = f2bf(qk[base + (size_t)(dq * 8 + j) * 2 * LDIM] * rn);
            *(uint4*)(dst + dq * 8) = *(const uint4*)tmp;
        }
    }
}

// Normalize v over d, emit bf16 in [c][token] layout.
__global__ void k_norm_v_t(const float* __restrict__ v, u16* __restrict__ vb) {
    int l = blockIdx.x * 256 + threadIdx.x;
    for (int h = 0; h < 4; ++h) {
        size_t base = (size_t)h * 128 * LDIM + l;
        float ss = 0.f;
        for (int dd = 0; dd < 128; ++dd) { float t = v[base + (size_t)dd * LDIM]; ss += t * t; }
        float rn = 1.f / (kEps + sqrtf(ss * (1.0f / 128.0f)));
        for (int dd = 0; dd < 128; ++dd)
            vb[base + (size_t)dd * LDIM] = f2bf(v[base + (size_t)dd * LDIM] * rn);
    }
}

// ---------------------------------------------------------------------------
// MFMA flash attention. TQ=128 (block), TK=64. 256 threads = 4 waves; each
// wave owns a 32-row strip. Q frags in registers. Fixed-max softmax (scores
// bounded by sqrt(d)=11.32 since q,k unit-normalized => exp never overflows).
// mfma_f32_16x16x32_bf16 layouts (m89-verified):
//   A[m=lane&15][k=quad*8+r], B[k=quad*8+r][n=lane&15], D[row=quad*4+r][col=lane&15]
#define KP 136   // Ks row pitch (u16): [j][d], +8 pad => 2-way banks
#define VP 72    // Vs/Ps row pitch (u16)
__launch_bounds__(256, 1)
__global__ void k_attn_mfma(const u16* __restrict__ q_t, const u16* __restrict__ k_t,
                            const u16* __restrict__ v_bf, const float* __restrict__ xs,
                            float* __restrict__ out) {
    __shared__ u16 Ks[64 * KP];    // [j][d]
    __shared__ u16 Vs[128 * VP];   // [d][j]
    __shared__ u16 Ps[128 * VP];   // [i][j] (per-wave 32-row strips)
    const int t = threadIdx.x;
    const int wave = t >> 6, lane = t & 63;
    const int quad = lane >> 4, ln = lane & 15;
    const int h  = blockIdx.y;
    const int i0 = blockIdx.x * 128;
    const size_t hbase = (size_t)h * LDIM * 128;

    // Q fragments (A-operand): [mt][ks], d = ks*32 + quad*8 + r
    bf16x8 qf[2][4];
    #pragma unroll
    for (int mt = 0; mt < 2; ++mt) {
        int row = i0 + wave * 32 + mt * 16 + ln;
        #pragma unroll
        for (int ks = 0; ks < 4; ++ks)
            qf[mt][ks] = *(const bf16x8*)(q_t + hbase + (size_t)row * 128 + ks * 32 + quad * 8);
    }

    f32x4 o_acc[2][8] = {};   // [mt][dt], D-layout rows = tokens
    float lsum[2][4] = {};    // per-lane partial row sums of P

    const u16* kg = k_t + hbase;
    const u16* vg = v_bf + hbase;

    // stage first K/V tile
    #pragma unroll
    for (int i = 0; i < 4; ++i) {
        int c = t + 256 * i;
        *(uint4*)&Ks[(c >> 4) * KP + (c & 15) * 8] =
            *(const uint4*)(kg + (size_t)(c >> 4) * 128 + (c & 15) * 8);
        *(uint4*)&Vs[(c >> 3) * VP + (c & 7) * 8] =
            *(const uint4*)(vg + (size_t)(c >> 3) * LDIM + (c & 7) * 8);
    }
    __syncthreads();

    for (int j0 = 0; j0 < LDIM; j0 += 64) {
        // prefetch next tile into registers (hidden under compute)
        uint4 kb[4], vb[4];
        const bool pf = (j0 + 64 < LDIM);
        if (pf) {
            #pragma unroll
            for (int i = 0; i < 4; ++i) {
                int c = t + 256 * i;
                kb[i] = *(const uint4*)(kg + (size_t)(j0 + 64 + (c >> 4)) * 128 + (c & 15) * 8);
                vb[i] = *(const uint4*)(vg + (size_t)(c >> 3) * LDIM + (j0 + 64) + (c & 7) * 8);
            }
        }

        // S = Q K^T : wave's 32 rows x 64 cols
        f32x4 s_acc[2][4] = {};
        #pragma unroll
        for (int ks = 0; ks < 4; ++ks) {
            bf16x8 bfr[4];
            #pragma unroll
            for (int nt = 0; nt < 4; ++nt)
                bfr[nt] = *(const bf16x8*)&Ks[(nt * 16 + ln) * KP + ks * 32 + quad * 8];
            #pragma unroll
            for (int mt = 0; mt < 2; ++mt)
                #pragma unroll
                for (int nt = 0; nt < 4; ++nt)
                    s_acc[mt][nt] = __builtin_amdgcn_mfma_f32_16x16x32_bf16(
                        qf[mt][ks], bfr[nt], s_acc[mt][nt], 0, 0, 0);
        }

        // P = exp(S) (no max subtraction needed: |S| <= 11.32); write bf16 to Ps
        #pragma unroll
        for (int mt = 0; mt < 2; ++mt) {
            int prow = wave * 32 + mt * 16 + quad * 4;
            #pragma unroll
            for (int nt = 0; nt < 4; ++nt)
                #pragma unroll
                for (int r = 0; r < 4; ++r) {
                    float p = __expf(s_acc[mt][nt][r]);
                    lsum[mt][r] += p;
                    Ps[(prow + r) * VP + nt * 16 + ln] = f2bf(p);
                }
        }

        // O += P V  (same-wave Ps RAW: DS ops in-order within a wave)
        #pragma unroll
        for (int ks = 0; ks < 2; ++ks) {
            bf16x8 ap[2];
            #pragma unroll
            for (int mt = 0; mt < 2; ++mt)
                ap[mt] = *(const bf16x8*)&Ps[(wave * 32 + mt * 16 + ln) * VP + ks * 32 + quad * 8];
            #pragma unroll
            for (int dt = 0; dt < 8; ++dt) {
                bf16x8 bv = *(const bf16x8*)&Vs[(dt * 16 + ln) * VP + ks * 32 + quad * 8];
                #pragma unroll
                for (int mt = 0; mt < 2; ++mt)
                    o_acc[mt][dt] = __builtin_amdgcn_mfma_f32_16x16x32_bf16(
                        ap[mt], bv, o_acc[mt][dt], 0, 0, 0);
            }
        }

        __syncthreads();
        if (pf) {
            #pragma unroll
            for (int i = 0; i < 4; ++i) {
                int c = t + 256 * i;
                *(uint4*)&Ks[(c >> 4) * KP + (c & 15) * 8] = kb[i];
                *(uint4*)&Vs[(c >> 3) * VP + (c & 7) * 8] = vb[i];
            }
        }
        __syncthreads();
    }

    // finalize row sums across the 16 lanes holding each row
    float rl[2][4];
    #pragma unroll
    for (int mt = 0; mt < 2; ++mt)
        #pragma unroll
        for (int r = 0; r < 4; ++r) {
            float s = lsum[mt][r];
            s += __shfl_xor(s, 1); s += __shfl_xor(s, 2);
            s += __shfl_xor(s, 4); s += __shfl_xor(s, 8);
            rl[mt][r] = 1.0f / s;
        }

    // epilogue: out = clip((xs + O/l)/sqrt(2)); float4 = 4 consecutive tokens
    #pragma unroll
    for (int mt = 0; mt < 2; ++mt) {
        int tok = i0 + wave * 32 + mt * 16 + quad * 4;
        #pragma unroll
        for (int dt = 0; dt < 8; ++dt) {
            int c = h * 128 + dt * 16 + ln;
            size_t gi = (size_t)c * LDIM + tok;
            float4 xv = *(const float4*)(xs + gi);
            float4 ov;
            ov.x = (xv.x + o_acc[mt][dt][0] * rl[mt][0]) * kInvSqrt2;
            ov.y = (xv.y + o_acc[mt][dt][1] * rl[mt][1]) * kInvSqrt2;
            ov.z = (xv.z + o_acc[mt][dt][2] * rl[mt][2]) * kInvSqrt2;
            ov.w = (xv.w + o_acc[mt][dt][3] * rl[mt][3]) * kInvSqrt2;
            ov.x = fminf(fmaxf(ov.x, -256.f), 256.f);
            ov.y = fminf(fmaxf(ov.y, -256.f), 256.f);
            ov.z = fminf(fmaxf(ov.z, -256.f), 256.f);
            ov.w = fminf(fmaxf(ov.w, -256.f), 256.f);
            *(float4*)(out + gi) = ov;
        }
    }
}

// ---------------------------------------------------------------------------
extern "C" void kernel_launch(void* const* d_in, const int* in_sizes, int n_in,
                              void* d_out, int out_size, void* d_ws, size_t ws_size,
                              hipStream_t stream) {
    const float* x      = (const float*)d_in[0];
    const float* emb    = (const float*)d_in[1];
    const float* pos    = (const float*)d_in[2];
    const float* eg     = (const float*)d_in[3];
    const float* w_res0 = (const float*)d_in[4];
    const float* w_depth= (const float*)d_in[5];
    const float* w_emb  = (const float*)d_in[6];
    const float* w_res1 = (const float*)d_in[7];
    const float* w_qk   = (const float*)d_in[8];
    const float* w_v    = (const float*)d_in[9];
    float* out = (float*)d_out;

    float* W  = (float*)d_ws;
    float* xn = W;                                   // 4M f: xn -> xs (in place)
    float* B1 = W + (size_t)4  * 1024 * 1024;        // 8M f: y1 -> y3 -> qk; then v_bf
    float* B2 = W + (size_t)12 * 1024 * 1024;        // 8M f: y2 -> pe; then v fp32 (lower 4M)
    float* cv = W + (size_t)20 * 1024 * 1024;        // 1024 f
    u16* v_bf = (u16*)B1;                            // 8 MB (after qk consumed)
    u16* q_t  = (u16*)(W + (size_t)16 * 1024 * 1024);// 8 MB
    u16* k_t  = (u16*)(W + (size_t)18 * 1024 * 1024);// 8 MB

    k_norm_x<<<32, 256, 0, stream>>>(x, xn);
    k_emb<<<256, 256, 0, stream>>>(w_emb, emb, eg, cv);
    // y1 = res0(xn): M=1024, K=512
    k_gemm<<<dim3(128, 16), 256, 0, stream>>>(w_res0, xn, B1, 512, kInvSqrt512);
    // y2 = silu(gconv(y1) * c)
    k_gconv<<<dim3(64, 16), 128, 0, stream>>>(B1, w_depth, cv, B2);
    // y3 = res1(y2): M=512, K=1024 -> B1
    k_gemm<<<dim3(128, 8), 256, 0, stream>>>(w_res1, B2, B1, 1024, kInvSqrt1024);
    // xs = (xn + y3)/sqrt(2), in place
    k_mpsum<<<16384, 256, 0, stream>>>(xn, B1, xn);
    // pe -> B2
    k_pe<<<16384, 256, 0, stream>>>(xn, pos, B2);
    // qk = w_qk @ pe: M=1024, K=1024 -> B1
    k_gemm<<<dim3(128, 16), 256, 0, stream>>>(w_qk, B2, B1, 1024, kInvSqrt1024);
    // q_t/k_t bf16 [h][token][d] (q scaled by 1/sqrt(d))
    k_norm_qk_t<<<32, 256, 0, stream>>>(B1, q_t, k_t);
    // v = w_v @ xs: M=512, K=512 -> B2 lower half (pe dead)
    k_gemm<<<dim3(128, 8), 256, 0, stream>>>(w_v, xn, B2, 512, kInvSqrt512);
    // v_bf bf16 [c][token] -> B1 (qk dead)
    k_norm_v_t<<<32, 256, 0, stream>>>(B2, v_bf);
    // attention + residual + clip
    k_attn_mfma<<<dim3(64, 4), 256, 0, stream>>>(q_t, k_t, v_bf, xn, out);
}

// Round 3
// 786.248 us; speedup vs baseline: 7.2885x; 2.4077x over previous
//
#include <hip/hip_runtime.h>
#include <math.h>

#define LDIM 8192   // H*W = 16*512
#define NC   512
#define NM   1024

typedef unsigned short u16;
typedef unsigned int   u32;
typedef short bf16x8 __attribute__((ext_vector_type(8)));
typedef float f32x4  __attribute__((ext_vector_type(4)));

static constexpr float kEps        = 1e-4f;
static constexpr float kInvSqrt512 = 0.044194173824159216f;
static constexpr float kInvSqrt1024= 0.03125f;
static constexpr float kInvSqrt1152= 0.029462782549439483f;
static constexpr float kQScale     = 0.08838834764831845f;   // 1/sqrt(128)
static constexpr float kInvSqrt2   = 0.7071067811865476f;
static constexpr float kInvSilu    = 1.0f / 0.596f;

__device__ __forceinline__ u16 f2bf(float f) {
    u32 u = __float_as_uint(f);
    u += 0x7fff + ((u >> 16) & 1);
    return (u16)(u >> 16);
}
__device__ __forceinline__ float bf2f(u16 h) { return __uint_as_float((u32)h << 16); }
__device__ __forceinline__ uint2 pk4(float a, float b, float c, float d) {
    uint2 r;
    r.x = (u32)f2bf(a) | ((u32)f2bf(b) << 16);
    r.y = (u32)f2bf(c) | ((u32)f2bf(d) << 16);
    return r;
}

// ---------------------------------------------------------------------------
// Weight prep: fp32->bf16 casts + gconv weight re-layout [co][ci][tap]->[tap][co][ci]
#define N_W0 524288
#define N_W1 524288
#define N_WQ 1048576
#define N_WV 262144
#define N_WT 1179648
__global__ void k_prep_w(const float* __restrict__ w0, const float* __restrict__ w1,
                         const float* __restrict__ wq, const float* __restrict__ wv,
                         const float* __restrict__ wd,
                         u16* __restrict__ w0b, u16* __restrict__ w1b,
                         u16* __restrict__ wqb, u16* __restrict__ wvb,
                         u16* __restrict__ wtb) {
    const int total = N_W0 + N_W1 + N_WQ + N_WV + N_WT;
    for (int i = blockIdx.x * 256 + threadIdx.x; i < total; i += gridDim.x * 256) {
        int idx = i;
        if (idx < N_W0) { w0b[idx] = f2bf(w0[idx]); continue; }
        idx -= N_W0;
        if (idx < N_W1) { w1b[idx] = f2bf(w1[idx]); continue; }
        idx -= N_W1;
        if (idx < N_WQ) { wqb[idx] = f2bf(wq[idx]); continue; }
        idx -= N_WQ;
        if (idx < N_WV) { wvb[idx] = f2bf(wv[idx]); continue; }
        idx -= N_WV;
        // wtb[tap][co][ci] = wd[co][ci][tap]
        int tap = idx >> 17;
        int rem = idx & 131071;
        int co = rem >> 7, ci = rem & 127;
        wtb[idx] = f2bf(wd[(co * 128 + ci) * 9 + tap]);
    }
}

// cvec[m] = emb_gain/sqrt(512) * sum_e w_emb[m,e]*emb[e] + 1
__global__ void k_emb(const float* __restrict__ w_emb, const float* __restrict__ emb,
                      const float* __restrict__ eg, float* __restrict__ cvec) {
    int wave = threadIdx.x >> 6, lane = threadIdx.x & 63;
    int m = blockIdx.x * 4 + wave;
    float s = 0.f;
    for (int e = lane; e < 512; e += 64) s += w_emb[(size_t)m * 512 + e] * emb[e];
    for (int off = 32; off; off >>= 1) s += __shfl_down(s, off);
    if (lane == 0) cvec[m] = eg[0] * kInvSqrt512 * s + 1.0f;
}

// ---------------------------------------------------------------------------
// Transpose f32 [512][8192] -> bf16 [8192][512], optional pixel-norm over C.
__launch_bounds__(256)
__global__ void k_tr_f2b(const float* __restrict__ in, u16* __restrict__ out, int do_norm) {
    __shared__ float T[64][65];
    __shared__ float red[4][64];
    __shared__ float rnS[64];
    const int t = threadIdx.x;
    const int l0 = blockIdx.x * 64;
    if (do_norm) {
        int ll = t & 63, cq = t >> 6;
        float ss = 0.f;
        for (int c = cq; c < 512; c += 4) {
            float v = in[(size_t)c * LDIM + l0 + ll];
            ss += v * v;
        }
        red[cq][ll] = ss;
        __syncthreads();
        if (t < 64)
            rnS[t] = 1.f / (kEps + sqrtf((red[0][t] + red[1][t] + red[2][t] + red[3][t]) * (1.0f / 512.0f)));
        __syncthreads();
    }
    for (int c0 = 0; c0 < 512; c0 += 64) {
        #pragma unroll
        for (int i = 0; i < 16; ++i) {
            int idx = t + 256 * i;
            int ci = idx >> 6, ll = idx & 63;
            T[ci][ll] = in[(size_t)(c0 + ci) * LDIM + l0 + ll];
        }
        __syncthreads();
        #pragma unroll
        for (int i = 0; i < 16; ++i) {
            int idx = t + 256 * i;
            int cc = idx & 63, lo = idx >> 6;
            float v = T[cc][lo];
            if (do_norm) v *= rnS[lo];
            out[(size_t)(l0 + lo) * 512 + c0 + cc] = f2bf(v);
        }
        __syncthreads();
    }
}

// Transpose bf16 [8192][512] -> [512][8192], out f32 (mode 0) or bf16 (mode 1)
__launch_bounds__(256)
__global__ void k_tr_b2x(const u16* __restrict__ in, void* __restrict__ outp, int mode) {
    __shared__ u16 T[64][72];
    const int t = threadIdx.x;
    const int lt = blockIdx.x & 127, ct = blockIdx.x >> 7;
    const int l0 = lt * 64, c0 = ct * 64;
    #pragma unroll
    for (int i = 0; i < 2; ++i) {
        int c = t + 256 * i;
        int ll = c >> 3, cc = c & 7;
        *(uint4*)&T[ll][cc * 8] = *(const uint4*)(in + (size_t)(l0 + ll) * 512 + c0 + cc * 8);
    }
    __syncthreads();
    int ll = t & 63;
    if (mode == 0) {
        float* out = (float*)outp;
        #pragma unroll
        for (int i = 0; i < 16; ++i) {
            int cj = (t >> 6) + 4 * i;
            out[(size_t)(c0 + cj) * LDIM + l0 + ll] = bf2f(T[ll][cj]);
        }
    } else {
        u16* out = (u16*)outp;
        #pragma unroll
        for (int i = 0; i < 16; ++i) {
            int cj = (t >> 6) + 4 * i;
            out[(size_t)(c0 + cj) * LDIM + l0 + ll] = T[ll][cj];
        }
    }
}

// ---------------------------------------------------------------------------
// bf16 NT-GEMM, token-major: Out[l][co] = scale * sum_k Xt[l][k] * W[co][k]
// Block: 128 l x 128 co, 4 waves (2x2 of 64co x 64l). BK=64.
__launch_bounds__(256, 2)
__global__ void k_gemm_tm(const u16* __restrict__ Xt, const u16* __restrict__ W,
                          u16* __restrict__ Out, int K, int M, float scale) {
    __shared__ u16 sm[18432];           // Xs[128][72] + Ws[128][72]; Sout[128][136] unions
    u16* Xs = sm;
    u16* Ws = sm + 9216;
    u16* Sout = sm;
    const int t = threadIdx.x;
    const int lane = t & 63, wave = t >> 6;
    const int quad = lane >> 4, ln = lane & 15;
    const int l0 = blockIdx.x * 128, m0 = blockIdx.y * 128;
    const int cs = (wave & 1) * 64, ls = (wave >> 1) * 64;

    // stage k0=0
    #pragma unroll
    for (int i = 0; i < 4; ++i) {
        int c = t + 256 * i;
        int row = c >> 3, cc = c & 7;
        *(uint4*)&Xs[row * 72 + cc * 8] = *(const uint4*)(Xt + (size_t)(l0 + row) * K + cc * 8);
        *(uint4*)&Ws[row * 72 + cc * 8] = *(const uint4*)(W + (size_t)(m0 + row) * K + cc * 8);
    }
    __syncthreads();

    f32x4 acc[4][4] = {};
    for (int k0 = 0; k0 < K; k0 += 64) {
        uint4 px[4], pw[4];
        const bool pf = (k0 + 64 < K);
        if (pf) {
            #pragma unroll
            for (int i = 0; i < 4; ++i) {
                int c = t + 256 * i;
                int row = c >> 3, cc = c & 7;
                px[i] = *(const uint4*)(Xt + (size_t)(l0 + row) * K + k0 + 64 + cc * 8);
                pw[i] = *(const uint4*)(W + (size_t)(m0 + row) * K + k0 + 64 + cc * 8);
            }
        }
        #pragma unroll
        for (int ks = 0; ks < 2; ++ks) {
            bf16x8 af[4], bf[4];
            #pragma unroll
            for (int mt = 0; mt < 4; ++mt)
                af[mt] = *(const bf16x8*)&Ws[(cs + mt * 16 + ln) * 72 + ks * 32 + quad * 8];
            #pragma unroll
            for (int nt = 0; nt < 4; ++nt)
                bf[nt] = *(const bf16x8*)&Xs[(ls + nt * 16 + ln) * 72 + ks * 32 + quad * 8];
            #pragma unroll
            for (int mt = 0; mt < 4; ++mt)
                #pragma unroll
                for (int nt = 0; nt < 4; ++nt)
                    acc[mt][nt] = __builtin_amdgcn_mfma_f32_16x16x32_bf16(af[mt], bf[nt], acc[mt][nt], 0, 0, 0);
        }
        __syncthreads();
        if (pf) {
            #pragma unroll
            for (int i = 0; i < 4; ++i) {
                int c = t + 256 * i;
                int row = c >> 3, cc = c & 7;
                *(uint4*)&Xs[row * 72 + cc * 8] = px[i];
                *(uint4*)&Ws[row * 72 + cc * 8] = pw[i];
            }
        }
        __syncthreads();
    }
    // epilogue via LDS gather: Sout[l][co], D rows = co (quad*4+r), cols = l (ln)
    #pragma unroll
    for (int mt = 0; mt < 4; ++mt)
        #pragma unroll
        for (int nt = 0; nt < 4; ++nt) {
            f32x4 a = acc[mt][nt];
            *(uint2*)&Sout[(ls + nt * 16 + ln) * 136 + cs + mt * 16 + quad * 4] =
                pk4(a[0] * scale, a[1] * scale, a[2] * scale, a[3] * scale);
        }
    __syncthreads();
    #pragma unroll
    for (int i = 0; i < 8; ++i) {
        int c = t + 256 * i;
        int row = c >> 4, cc = c & 15;
        *(uint4*)(Out + (size_t)(l0 + row) * M + m0 + cc * 8) = *(uint4*)&Sout[row * 136 + cc * 8];
    }
}

// ---------------------------------------------------------------------------
// Grouped 1x9 conv as 9-tap MFMA NT-GEMM + gate + mp_silu.
// Block: 64 l x 128 co (one group). Wave: 32 co (mt2) x 64 l (nt4).
__launch_bounds__(256, 4)
__global__ void k_gconv_tm(const u16* __restrict__ y1t, const u16* __restrict__ wtb,
                           const float* __restrict__ cvec, u16* __restrict__ y2t) {
    __shared__ u16 sm[9792];            // Y[72][136]; Sout[64][136] union
    u16* Y = sm;
    u16* Sout = sm;
    const int t = threadIdx.x;
    const int lane = t & 63, wave = t >> 6;
    const int quad = lane >> 4, ln = lane & 15;
    const int l0 = blockIdx.x * 64;
    const int m0 = blockIdx.y * 128;
    const int g = m0 >> 7;

    // stage Y rows l0-4 .. l0+67, ci = g*128..+127
    for (int c = t; c < 1152; c += 256) {
        int row = c >> 4, cc = c & 15;
        int gl = l0 - 4 + row;
        gl = min(max(gl, 0), LDIM - 1);
        *(uint4*)&Y[row * 136 + cc * 8] = *(const uint4*)(y1t + (size_t)gl * 1024 + g * 128 + cc * 8);
    }
    __syncthreads();

    f32x4 acc[2][4] = {};
    const bf16x8 zv = {};
    for (int tap = 0; tap < 9; ++tap) {
        #pragma unroll
        for (int ks = 0; ks < 4; ++ks) {
            bf16x8 af[2], bfr[4];
            #pragma unroll
            for (int mt = 0; mt < 2; ++mt)
                af[mt] = *(const bf16x8*)(wtb + ((size_t)tap * 1024 + m0 + wave * 32 + mt * 16 + ln) * 128 + ks * 32 + quad * 8);
            #pragma unroll
            for (int nt = 0; nt < 4; ++nt) {
                bfr[nt] = *(const bf16x8*)&Y[(nt * 16 + ln + tap) * 136 + ks * 32 + quad * 8];
                int w = ((l0 + nt * 16 + ln) & 511) + tap - 4;
                bool ok = (w >= 0) && (w < 512);
                bfr[nt] = ok ? bfr[nt] : zv;
            }
            #pragma unroll
            for (int mt = 0; mt < 2; ++mt)
                #pragma unroll
                for (int nt = 0; nt < 4; ++nt)
                    acc[mt][nt] = __builtin_amdgcn_mfma_f32_16x16x32_bf16(af[mt], bfr[nt], acc[mt][nt], 0, 0, 0);
        }
    }
    __syncthreads();
    // epilogue: z = acc*s*c; silu; Sout[l][co]
    #pragma unroll
    for (int mt = 0; mt < 2; ++mt) {
        float4 cv = *(const float4*)(cvec + m0 + wave * 32 + mt * 16 + quad * 4);
        #pragma unroll
        for (int nt = 0; nt < 4; ++nt) {
            float z[4], o[4];
            #pragma unroll
            for (int r = 0; r < 4; ++r) {
                z[r] = acc[mt][nt][r] * kInvSqrt1152 * ((const float*)&cv)[r];
                float sig = 1.0f / (1.0f + __expf(-z[r]));
                o[r] = z[r] * sig * kInvSilu;
            }
            *(uint2*)&Sout[(nt * 16 + ln) * 136 + wave * 32 + mt * 16 + quad * 4] =
                pk4(o[0], o[1], o[2], o[3]);
        }
    }
    __syncthreads();
    #pragma unroll
    for (int i = 0; i < 4; ++i) {
        int c = t + 256 * i;
        int row = c >> 4, cc = c & 15;
        *(uint4*)(y2t + (size_t)(l0 + row) * 1024 + m0 + cc * 8) = *(uint4*)&Sout[row * 136 + cc * 8];
    }
}

// ---------------------------------------------------------------------------
// xs_t = (xt + y3t)/sqrt(2), bf16 token-major, 8 elems/thread
__global__ void k_mpsum_t(const u16* __restrict__ a, const u16* __restrict__ b,
                          u16* __restrict__ out) {
    size_t base = ((size_t)blockIdx.x * 256 + threadIdx.x) * 8;
    uint4 av = *(const uint4*)(a + base);
    uint4 bv = *(const uint4*)(b + base);
    const u16* ap = (const u16*)&av;
    const u16* bp = (const u16*)&bv;
    u16 o[8];
    #pragma unroll
    for (int i = 0; i < 8; ++i) o[i] = f2bf((bf2f(ap[i]) + bf2f(bp[i])) * kInvSqrt2);
    *(uint4*)(out + base) = *(uint4*)o;
}

// pe_t[l][2c]=xs, [2c+1]=xs*pos  (8 c's per thread)
__global__ void k_pe_t(const u16* __restrict__ xs, const u16* __restrict__ pos,
                       u16* __restrict__ pe) {
    int idx = blockIdx.x * 256 + threadIdx.x;
    int l = idx >> 6, cq = idx & 63;
    size_t src = (size_t)l * 512 + cq * 8;
    uint4 xv = *(const uint4*)(xs + src);
    uint4 pv = *(const uint4*)(pos + src);
    const u16* xp = (const u16*)&xv;
    const u16* pp = (const u16*)&pv;
    u16 o[16];
    #pragma unroll
    for (int i = 0; i < 8; ++i) {
        o[2 * i] = xp[i];
        o[2 * i + 1] = f2bf(bf2f(xp[i]) * bf2f(pp[i]));
    }
    u16* dst = pe + (size_t)l * 1024 + cq * 16;
    *(uint4*)dst = *(uint4*)&o[0];
    *(uint4*)(dst + 8) = *(uint4*)&o[8];
}

// ---------------------------------------------------------------------------
// qk norm: qk_t [L][1024] bf16 -> q_t/k_t [4][L][128] bf16; q scaled by 1/sqrt(d).
// One wave per token; lane covers 16 consecutive channels (h = lane>>4).
__global__ void k_norm_qk2(const u16* __restrict__ qk, u16* __restrict__ q_t,
                           u16* __restrict__ k_t) {
    int wave = threadIdx.x >> 6, lane = threadIdx.x & 63;
    int l = blockIdx.x * 4 + wave;
    const u16* row = qk + (size_t)l * 1024 + lane * 16;
    uint4 a = *(const uint4*)row;
    uint4 b = *(const uint4*)(row + 8);
    const u16* vp = (const u16*)&a;
    const u16* wp = (const u16*)&b;
    float v[16];
    #pragma unroll
    for (int i = 0; i < 8; ++i) { v[i] = bf2f(vp[i]); v[8 + i] = bf2f(wp[i]); }
    float ss0 = 0.f, ss1 = 0.f;
    #pragma unroll
    for (int i = 0; i < 8; ++i) { ss0 += v[2 * i] * v[2 * i]; ss1 += v[2 * i + 1] * v[2 * i + 1]; }
    #pragma unroll
    for (int off = 1; off < 16; off <<= 1) {
        ss0 += __shfl_xor(ss0, off);
        ss1 += __shfl_xor(ss1, off);
    }
    float rn0 = kQScale / (kEps + sqrtf(ss0 * (1.0f / 128.0f)));
    float rn1 = 1.0f / (kEps + sqrtf(ss1 * (1.0f / 128.0f)));
    int h = lane >> 4;
    u16 qo[8], ko[8];
    #pragma unroll
    for (int i = 0; i < 8; ++i) {
        qo[i] = f2bf(v[2 * i] * rn0);
        ko[i] = f2bf(v[2 * i + 1] * rn1);
    }
    size_t dst = ((size_t)h * LDIM + l) * 128 + (lane & 15) * 8;
    *(uint4*)(q_t + dst) = *(uint4*)qo;
    *(uint4*)(k_t + dst) = *(uint4*)ko;
}

// v norm in place: v_t [L][512] bf16, norm over 128-chunk per head.
__global__ void k_norm_v2(u16* __restrict__ v_t) {
    int wave = threadIdx.x >> 6, lane = threadIdx.x & 63;
    int l = blockIdx.x * 4 + wave;
    u16* p = v_t + (size_t)l * 512 + lane * 8;
    uint4 a = *(const uint4*)p;
    const u16* vp = (const u16*)&a;
    float v[8], ss = 0.f;
    #pragma unroll
    for (int i = 0; i < 8; ++i) { v[i] = bf2f(vp[i]); ss += v[i] * v[i]; }
    #pragma unroll
    for (int off = 1; off < 16; off <<= 1) ss += __shfl_xor(ss, off);
    float rn = 1.0f / (kEps + sqrtf(ss * (1.0f / 128.0f)));
    u16 o[8];
    #pragma unroll
    for (int i = 0; i < 8; ++i) o[i] = f2bf(v[i] * rn);
    *(uint4*)p = *(uint4*)o;
}

// ---------------------------------------------------------------------------
// MFMA flash attention, S^T formulation, K-split=2.
// Block: TQ=128 (4 waves x 32 rows), TK=64. Outputs partial O (bf16) + lsum.
__launch_bounds__(256, 2)
__global__ void k_attn2(const u16* __restrict__ q_t, const u16* __restrict__ k_t,
                        const u16* __restrict__ vt2, u16* __restrict__ Opart,
                        float* __restrict__ lsumG) {
    __shared__ u16 Ks[64 * 136];    // [j][d]
    __shared__ u16 Vs[128 * 72];    // [d][j]
    __shared__ u16 Ps[128 * 72];    // [i][j]
    const int t = threadIdx.x;
    const int lane = t & 63, wave = t >> 6;
    const int quad = lane >> 4, ln = lane & 15;
    const int h = blockIdx.y, sp = blockIdx.z;
    const int i0 = blockIdx.x * 128;
    const int jb0 = sp * 4096, jend = jb0 + 4096;
    const u16* qg = q_t + (size_t)h * LDIM * 128;
    const u16* kg = k_t + (size_t)h * LDIM * 128;
    const u16* vg = vt2 + (size_t)h * 128 * LDIM;

    bf16x8 qf[2][4];
    #pragma unroll
    for (int mt = 0; mt < 2; ++mt) {
        int row = i0 + wave * 32 + mt * 16 + ln;
        #pragma unroll
        for (int ks = 0; ks < 4; ++ks)
            qf[mt][ks] = *(const bf16x8*)(qg + (size_t)row * 128 + ks * 32 + quad * 8);
    }

    f32x4 o_acc[2][8] = {};
    float lsum[2] = {0.f, 0.f};

    // stage first tile
    #pragma unroll
    for (int i = 0; i < 4; ++i) {
        int c = t + 256 * i;
        {
            int row = c >> 4, cc = c & 15;
            *(uint4*)&Ks[row * 136 + cc * 8] = *(const uint4*)(kg + (size_t)(jb0 + row) * 128 + cc * 8);
        }
        {
            int row = c >> 3, cc = c & 7;
            *(uint4*)&Vs[row * 72 + cc * 8] = *(const uint4*)(vg + (size_t)row * LDIM + jb0 + cc * 8);
        }
    }
    __syncthreads();

    for (int jb = jb0; jb < jend; jb += 64) {
        uint4 kx[4], vx[4];
        const bool pf = (jb + 64 < jend);
        if (pf) {
            #pragma unroll
            for (int i = 0; i < 4; ++i) {
                int c = t + 256 * i;
                kx[i] = *(const uint4*)(kg + (size_t)(jb + 64 + (c >> 4)) * 128 + (c & 15) * 8);
                vx[i] = *(const uint4*)(vg + (size_t)(c >> 3) * LDIM + jb + 64 + (c & 7) * 8);
            }
        }
        // S^T = K Q^T: st[jt][mt], D rows = j, cols = i
        f32x4 st[4][2] = {};
        #pragma unroll
        for (int ks = 0; ks < 4; ++ks) {
            bf16x8 af[4];
            #pragma unroll
            for (int jt = 0; jt < 4; ++jt)
                af[jt] = *(const bf16x8*)&Ks[(jt * 16 + ln) * 136 + ks * 32 + quad * 8];
            #pragma unroll
            for (int jt = 0; jt < 4; ++jt)
                #pragma unroll
                for (int mt = 0; mt < 2; ++mt)
                    st[jt][mt] = __builtin_amdgcn_mfma_f32_16x16x32_bf16(af[jt], qf[mt][ks], st[jt][mt], 0, 0, 0);
        }
        // exp (fixed-max: |S|<=sqrt(d)) -> Ps[i][j], b64 writes (4 consecutive j)
        #pragma unroll
        for (int jt = 0; jt < 4; ++jt)
            #pragma unroll
            for (int mt = 0; mt < 2; ++mt) {
                float p0 = __expf(st[jt][mt][0]);
                float p1 = __expf(st[jt][mt][1]);
                float p2 = __expf(st[jt][mt][2]);
                float p3 = __expf(st[jt][mt][3]);
                lsum[mt] += p0 + p1 + p2 + p3;
                *(uint2*)&Ps[(wave * 32 + mt * 16 + ln) * 72 + jt * 16 + quad * 4] = pk4(p0, p1, p2, p3);
            }
        // O += P V (per-wave rows; in-wave DS RAW is in-order)
        #pragma unroll
        for (int ks = 0; ks < 2; ++ks) {
            bf16x8 ap[2];
            #pragma unroll
            for (int mt = 0; mt < 2; ++mt)
                ap[mt] = *(const bf16x8*)&Ps[(wave * 32 + mt * 16 + ln) * 72 + ks * 32 + quad * 8];
            #pragma unroll
            for (int dt = 0; dt < 8; ++dt) {
                bf16x8 bv = *(const bf16x8*)&Vs[(dt * 16 + ln) * 72 + ks * 32 + quad * 8];
                #pragma unroll
                for (int mt = 0; mt < 2; ++mt)
                    o_acc[mt][dt] = __builtin_amdgcn_mfma_f32_16x16x32_bf16(ap[mt], bv, o_acc[mt][dt], 0, 0, 0);
            }
        }
        __syncthreads();
        if (pf) {
            #pragma unroll
            for (int i = 0; i < 4; ++i) {
                int c = t + 256 * i;
                *(uint4*)&Ks[(c >> 4) * 136 + (c & 15) * 8] = kx[i];
                *(uint4*)&Vs[(c >> 3) * 72 + (c & 7) * 8] = vx[i];
            }
        }
        __syncthreads();
    }

    // row sums (reduce across quads: lanes ln, ln+16, ln+32, ln+48)
    #pragma unroll
    for (int mt = 0; mt < 2; ++mt) {
        float s = lsum[mt];
        s += __shfl_xor(s, 16);
        s += __shfl_xor(s, 32);
        if (quad == 0)
            lsumG[(size_t)(sp * 4 + h) * LDIM + i0 + wave * 32 + mt * 16 + ln] = s;
    }
    // partial O: bf16, [sp][c=h*128+d][L], 4 consecutive tokens per lane
    u16* og = Opart + (size_t)sp * 512 * LDIM;
    #pragma unroll
    for (int mt = 0; mt < 2; ++mt)
        #pragma unroll
        for (int dt = 0; dt < 8; ++dt) {
            f32x4 o = o_acc[mt][dt];
            *(uint2*)(og + (size_t)(h * 128 + dt * 16 + ln) * LDIM + i0 + wave * 32 + mt * 16 + quad * 4) =
                pk4(o[0], o[1], o[2], o[3]);
        }
}

// combine: out[c][l] = clip((xs + (O0+O1)/(l0+l1)) / sqrt(2))
__global__ void k_combine(const u16* __restrict__ Opart, const float* __restrict__ lsumG,
                          const float* __restrict__ xs_cl, float* __restrict__ out) {
    int idx = blockIdx.x * 256 + threadIdx.x;   // 1M threads, 4 l's each
    int c = idx >> 11;
    int lq = (idx & 2047) * 4;
    int h = c >> 7;
    uint2 a = *(const uint2*)(Opart + (size_t)c * LDIM + lq);
    uint2 b = *(const uint2*)(Opart + (size_t)(512 + c) * LDIM + lq);
    float4 s0 = *(const float4*)(lsumG + (size_t)h * LDIM + lq);
    float4 s1 = *(const float4*)(lsumG + (size_t)(4 + h) * LDIM + lq);
    float4 xv = *(const float4*)(xs_cl + (size_t)c * LDIM + lq);
    const u16* ap = (const u16*)&a;
    const u16* bp = (const u16*)&b;
    float ls[4] = {s0.x + s1.x, s0.y + s1.y, s0.z + s1.z, s0.w + s1.w};
    float xi[4] = {xv.x, xv.y, xv.z, xv.w};
    float4 o;
    float* op = (float*)&o;
    #pragma unroll
    for (int r = 0; r < 4; ++r) {
        float ov = (bf2f(ap[r]) + bf2f(bp[r])) / ls[r];
        float val = (xi[r] + ov) * kInvSqrt2;
        op[r] = fminf(fmaxf(val, -256.f), 256.f);
    }
    *(float4*)(out + (size_t)c * LDIM + lq) = o;
}

// ---------------------------------------------------------------------------
extern "C" void kernel_launch(void* const* d_in, const int* in_sizes, int n_in,
                              void* d_out, int out_size, void* d_ws, size_t ws_size,
                              hipStream_t stream) {
    const float* x      = (const float*)d_in[0];
    const float* emb    = (const float*)d_in[1];
    const float* pos    = (const float*)d_in[2];
    const float* eg     = (const float*)d_in[3];
    const float* w_res0 = (const float*)d_in[4];
    const float* w_depth= (const float*)d_in[5];
    const float* w_emb  = (const float*)d_in[6];
    const float* w_res1 = (const float*)d_in[7];
    const float* w_qk   = (const float*)d_in[8];
    const float* w_v    = (const float*)d_in[9];
    float* out = (float*)d_out;

    char* W = (char*)d_ws;
    const size_t MiB = 1024 * 1024;
    u16*   xt    = (u16*)(W);                      // 8 MiB  [8192][512]
    u16*   pos_t = (u16*)(W + 8 * MiB);            // 8 MiB; later vt2
    u16*   w0b   = (u16*)(W + 16 * MiB);
    u16*   w1b   = (u16*)(W + 17 * MiB);
    u16*   wqb   = (u16*)(W + 18 * MiB);
    u16*   wvb   = (u16*)(W + 20 * MiB);
    u16*   wtb   = (u16*)(W + 20 * MiB + 512 * 1024);
    float* cvec  = (float*)(W + 22 * MiB + 768 * 1024);
    float* lsumG = (float*)(W + 23 * MiB);         // 256 KiB
    u16*   bufD  = (u16*)(W + 24 * MiB);           // 16 MiB: y1t -> qk_t -> xs_cl
    u16*   bufE  = (u16*)(W + 40 * MiB);           // 16 MiB: y2t -> pe_t -> v_t -> Opart
    u16*   k_t   = (u16*)(W + 56 * MiB);           // 8 MiB
    u16*   xs_t  = (u16*)(W + 64 * MiB);           // 8 MiB
    u16*   bufH  = (u16*)(W + 72 * MiB);           // 8 MiB: y3t -> q_t
    u16*   vt2   = pos_t;
    float* xs_cl = (float*)bufD;

    k_prep_w<<<2048, 256, 0, stream>>>(w_res0, w_res1, w_qk, w_v, w_depth,
                                       w0b, w1b, wqb, wvb, wtb);
    k_emb<<<256, 256, 0, stream>>>(w_emb, emb, eg, cvec);
    k_tr_f2b<<<128, 256, 0, stream>>>(x, xt, 1);
    k_tr_f2b<<<128, 256, 0, stream>>>(pos, pos_t, 0);
    // y1 = res0(xn): [L][1024]
    k_gemm_tm<<<dim3(64, 8), 256, 0, stream>>>(xt, w0b, bufD, 512, 1024, kInvSqrt512);
    // y2 = silu(gconv(y1)*c): [L][1024]
    k_gconv_tm<<<dim3(128, 8), 256, 0, stream>>>(bufD, wtb, cvec, bufE);
    // y3 = res1(y2): [L][512]
    k_gemm_tm<<<dim3(64, 4), 256, 0, stream>>>(bufE, w1b, bufH, 1024, 512, kInvSqrt1024);
    // xs = (xn + y3)/sqrt(2)
    k_mpsum_t<<<2048, 256, 0, stream>>>(xt, bufH, xs_t);
    // pe
    k_pe_t<<<2048, 256, 0, stream>>>(xs_t, pos_t, bufE);
    // qk = wqk(pe): [L][1024]
    k_gemm_tm<<<dim3(64, 8), 256, 0, stream>>>(bufE, wqb, bufD, 1024, 1024, kInvSqrt1024);
    // q/k norm + head-split
    k_norm_qk2<<<2048, 256, 0, stream>>>(bufD, bufH, k_t);
    // xs channel-major fp32 (for final combine)
    k_tr_b2x<<<1024, 256, 0, stream>>>(xs_t, xs_cl, 0);
    // v = wv(xs): [L][512]
    k_gemm_tm<<<dim3(64, 4), 256, 0, stream>>>(xs_t, wvb, bufE, 512, 512, kInvSqrt512);
    k_norm_v2<<<2048, 256, 0, stream>>>(bufE);
    // v -> [512][L]
    k_tr_b2x<<<1024, 256, 0, stream>>>(bufE, vt2, 1);
    // attention partials (K-split 2)
    k_attn2<<<dim3(64, 4, 2), 256, 0, stream>>>(bufH, k_t, vt2, bufE, lsumG);
    // combine + residual + clip
    k_combine<<<4096, 256, 0, stream>>>(bufE, lsumG, xs_cl, out);
}

// Round 4
// 784.534 us; speedup vs baseline: 7.3044x; 1.0022x over previous
//
#include <hip/hip_runtime.h>
#include <math.h>

#define LDIM 8192   // H*W = 16*512
#define NC   512
#define NM   1024

typedef unsigned short u16;
typedef unsigned int   u32;
typedef short bf16x8 __attribute__((ext_vector_type(8)));
typedef float f32x4  __attribute__((ext_vector_type(4)));

static constexpr float kEps        = 1e-4f;
static constexpr float kInvSqrt512 = 0.044194173824159216f;
static constexpr float kInvSqrt1024= 0.03125f;
static constexpr float kInvSqrt1152= 0.029462782549439483f;
static constexpr float kQScale     = 0.08838834764831845f;   // 1/sqrt(128)
static constexpr float kInvSqrt2   = 0.7071067811865476f;
static constexpr float kInvSilu    = 1.0f / 0.596f;

__device__ __forceinline__ u16 f2bf(float f) {
    u32 u = __float_as_uint(f);
    u += 0x7fff + ((u >> 16) & 1);
    return (u16)(u >> 16);
}
__device__ __forceinline__ float bf2f(u16 h) { return __uint_as_float((u32)h << 16); }
__device__ __forceinline__ uint2 pk4(float a, float b, float c, float d) {
    uint2 r;
    r.x = (u32)f2bf(a) | ((u32)f2bf(b) << 16);
    r.y = (u32)f2bf(c) | ((u32)f2bf(d) << 16);
    return r;
}

// ---------------------------------------------------------------------------
// Weight prep: fp32->bf16 casts + gconv weight re-layout [co][ci][tap]->[tap][co][ci]
#define N_W0 524288
#define N_W1 524288
#define N_WQ 1048576
#define N_WV 262144
#define N_WT 1179648
__global__ void k_prep_w(const float* __restrict__ w0, const float* __restrict__ w1,
                         const float* __restrict__ wq, const float* __restrict__ wv,
                         const float* __restrict__ wd,
                         u16* __restrict__ w0b, u16* __restrict__ w1b,
                         u16* __restrict__ wqb, u16* __restrict__ wvb,
                         u16* __restrict__ wtb) {
    const int total = N_W0 + N_W1 + N_WQ + N_WV + N_WT;
    for (int i = blockIdx.x * 256 + threadIdx.x; i < total; i += gridDim.x * 256) {
        int idx = i;
        if (idx < N_W0) { w0b[idx] = f2bf(w0[idx]); continue; }
        idx -= N_W0;
        if (idx < N_W1) { w1b[idx] = f2bf(w1[idx]); continue; }
        idx -= N_W1;
        if (idx < N_WQ) { wqb[idx] = f2bf(wq[idx]); continue; }
        idx -= N_WQ;
        if (idx < N_WV) { wvb[idx] = f2bf(wv[idx]); continue; }
        idx -= N_WV;
        int tap = idx >> 17;
        int rem = idx & 131071;
        int co = rem >> 7, ci = rem & 127;
        wtb[idx] = f2bf(wd[(co * 128 + ci) * 9 + tap]);
    }
}

// cvec[m] = emb_gain/sqrt(512) * sum_e w_emb[m,e]*emb[e] + 1
__global__ void k_emb(const float* __restrict__ w_emb, const float* __restrict__ emb,
                      const float* __restrict__ eg, float* __restrict__ cvec) {
    int wave = threadIdx.x >> 6, lane = threadIdx.x & 63;
    int m = blockIdx.x * 4 + wave;
    float s = 0.f;
    for (int e = lane; e < 512; e += 64) s += w_emb[(size_t)m * 512 + e] * emb[e];
    for (int off = 32; off; off >>= 1) s += __shfl_down(s, off);
    if (lane == 0) cvec[m] = eg[0] * kInvSqrt512 * s + 1.0f;
}

// ---------------------------------------------------------------------------
// rn[l] = 1/(eps + sqrt(mean_c x^2))  grid 128 x 256
__global__ void k_rn(const float* __restrict__ x, float* __restrict__ rn) {
    __shared__ float red[4][64];
    int t = threadIdx.x;
    int ll = t & 63, qtr = t >> 6;
    int l = blockIdx.x * 64 + ll;
    float ss = 0.f;
    for (int c = qtr * 128; c < (qtr + 1) * 128; ++c) {
        float v = x[(size_t)c * LDIM + l];
        ss += v * v;
    }
    red[qtr][ll] = ss;
    __syncthreads();
    if (t < 64)
        rn[blockIdx.x * 64 + t] =
            1.f / (kEps + sqrtf((red[0][t] + red[1][t] + red[2][t] + red[3][t]) * (1.0f / 512.0f)));
}

// Tiled transpose f32 [512][8192] -> bf16 [8192][512], optional per-l scale rn.
// grid (128 l-tiles, 8 c-tiles), 256 threads.
__launch_bounds__(256)
__global__ void k_tr2(const float* __restrict__ in, const float* __restrict__ rn,
                      u16* __restrict__ out) {
    __shared__ float T[64][65];
    const int t = threadIdx.x;
    const int l0 = blockIdx.x * 64, c0 = blockIdx.y * 64;
    #pragma unroll
    for (int i = 0; i < 16; ++i) {
        int idx = t + 256 * i;
        int ci = idx >> 6, ll = idx & 63;
        T[ci][ll] = in[(size_t)(c0 + ci) * LDIM + l0 + ll];
    }
    __syncthreads();
    int lo = t >> 2, cc0 = (t & 3) * 16;
    float s = rn ? rn[l0 + lo] : 1.0f;
    u16 tmp[16];
    #pragma unroll
    for (int j = 0; j < 16; ++j) tmp[j] = f2bf(T[cc0 + j][lo] * s);
    u16* dst = out + (size_t)(l0 + lo) * 512 + c0 + cc0;
    *(uint4*)dst = *(uint4*)&tmp[0];
    *(uint4*)(dst + 8) = *(uint4*)&tmp[8];
}

// Transpose bf16 [8192][512] -> [512][8192], out f32 (mode 0) or bf16 (mode 1)
__launch_bounds__(256)
__global__ void k_tr_b2x(const u16* __restrict__ in, void* __restrict__ outp, int mode) {
    __shared__ u16 T[64][72];
    const int t = threadIdx.x;
    const int lt = blockIdx.x & 127, ct = blockIdx.x >> 7;
    const int l0 = lt * 64, c0 = ct * 64;
    #pragma unroll
    for (int i = 0; i < 2; ++i) {
        int c = t + 256 * i;
        int ll = c >> 3, cc = c & 7;
        *(uint4*)&T[ll][cc * 8] = *(const uint4*)(in + (size_t)(l0 + ll) * 512 + c0 + cc * 8);
    }
    __syncthreads();
    int ll = t & 63;
    if (mode == 0) {
        float* out = (float*)outp;
        #pragma unroll
        for (int i = 0; i < 16; ++i) {
            int cj = (t >> 6) + 4 * i;
            out[(size_t)(c0 + cj) * LDIM + l0 + ll] = bf2f(T[ll][cj]);
        }
    } else {
        u16* out = (u16*)outp;
        #pragma unroll
        for (int i = 0; i < 16; ++i) {
            int cj = (t >> 6) + 4 * i;
            out[(size_t)(c0 + cj) * LDIM + l0 + ll] = T[ll][cj];
        }
    }
}

// ---------------------------------------------------------------------------
// bf16 NT-GEMM, token-major: Out[l][co] = scale * sum_k Xt[l][k] * W[co][k]
__launch_bounds__(256, 2)
__global__ void k_gemm_tm(const u16* __restrict__ Xt, const u16* __restrict__ W,
                          u16* __restrict__ Out, int K, int M, float scale) {
    __shared__ u16 sm[18432];           // Xs[128][72] + Ws[128][72]; Sout[128][136]
    u16* Xs = sm;
    u16* Ws = sm + 9216;
    u16* Sout = sm;
    const int t = threadIdx.x;
    const int lane = t & 63, wave = t >> 6;
    const int quad = lane >> 4, ln = lane & 15;
    const int l0 = blockIdx.x * 128, m0 = blockIdx.y * 128;
    const int cs = (wave & 1) * 64, ls = (wave >> 1) * 64;

    #pragma unroll
    for (int i = 0; i < 4; ++i) {
        int c = t + 256 * i;
        int row = c >> 3, cc = c & 7;
        *(uint4*)&Xs[row * 72 + cc * 8] = *(const uint4*)(Xt + (size_t)(l0 + row) * K + cc * 8);
        *(uint4*)&Ws[row * 72 + cc * 8] = *(const uint4*)(W + (size_t)(m0 + row) * K + cc * 8);
    }
    __syncthreads();

    f32x4 acc[4][4] = {};
    for (int k0 = 0; k0 < K; k0 += 64) {
        uint4 px[4], pw[4];
        const bool pf = (k0 + 64 < K);
        if (pf) {
            #pragma unroll
            for (int i = 0; i < 4; ++i) {
                int c = t + 256 * i;
                int row = c >> 3, cc = c & 7;
                px[i] = *(const uint4*)(Xt + (size_t)(l0 + row) * K + k0 + 64 + cc * 8);
                pw[i] = *(const uint4*)(W + (size_t)(m0 + row) * K + k0 + 64 + cc * 8);
            }
        }
        #pragma unroll
        for (int ks = 0; ks < 2; ++ks) {
            bf16x8 af[4], bf[4];
            #pragma unroll
            for (int mt = 0; mt < 4; ++mt)
                af[mt] = *(const bf16x8*)&Ws[(cs + mt * 16 + ln) * 72 + ks * 32 + quad * 8];
            #pragma unroll
            for (int nt = 0; nt < 4; ++nt)
                bf[nt] = *(const bf16x8*)&Xs[(ls + nt * 16 + ln) * 72 + ks * 32 + quad * 8];
            #pragma unroll
            for (int mt = 0; mt < 4; ++mt)
                #pragma unroll
                for (int nt = 0; nt < 4; ++nt)
                    acc[mt][nt] = __builtin_amdgcn_mfma_f32_16x16x32_bf16(af[mt], bf[nt], acc[mt][nt], 0, 0, 0);
        }
        __syncthreads();
        if (pf) {
            #pragma unroll
            for (int i = 0; i < 4; ++i) {
                int c = t + 256 * i;
                int row = c >> 3, cc = c & 7;
                *(uint4*)&Xs[row * 72 + cc * 8] = px[i];
                *(uint4*)&Ws[row * 72 + cc * 8] = pw[i];
            }
        }
        __syncthreads();
    }
    #pragma unroll
    for (int mt = 0; mt < 4; ++mt)
        #pragma unroll
        for (int nt = 0; nt < 4; ++nt) {
            f32x4 a = acc[mt][nt];
            *(uint2*)&Sout[(ls + nt * 16 + ln) * 136 + cs + mt * 16 + quad * 4] =
                pk4(a[0] * scale, a[1] * scale, a[2] * scale, a[3] * scale);
        }
    __syncthreads();
    #pragma unroll
    for (int i = 0; i < 8; ++i) {
        int c = t + 256 * i;
        int row = c >> 4, cc = c & 15;
        *(uint4*)(Out + (size_t)(l0 + row) * M + m0 + cc * 8) = *(uint4*)&Sout[row * 136 + cc * 8];
    }
}

// ---------------------------------------------------------------------------
// Grouped 1x9 conv as 9-tap MFMA NT-GEMM + gate + mp_silu.
__launch_bounds__(256, 4)
__global__ void k_gconv_tm(const u16* __restrict__ y1t, const u16* __restrict__ wtb,
                           const float* __restrict__ cvec, u16* __restrict__ y2t) {
    __shared__ u16 sm[9792];            // Y[72][136]; Sout[64][136]
    u16* Y = sm;
    u16* Sout = sm;
    const int t = threadIdx.x;
    const int lane = t & 63, wave = t >> 6;
    const int quad = lane >> 4, ln = lane & 15;
    const int l0 = blockIdx.x * 64;
    const int m0 = blockIdx.y * 128;
    const int g = m0 >> 7;

    for (int c = t; c < 1152; c += 256) {
        int row = c >> 4, cc = c & 15;
        int gl = l0 - 4 + row;
        gl = min(max(gl, 0), LDIM - 1);
        *(uint4*)&Y[row * 136 + cc * 8] = *(const uint4*)(y1t + (size_t)gl * 1024 + g * 128 + cc * 8);
    }
    __syncthreads();

    f32x4 acc[2][4] = {};
    const bf16x8 zv = {};
    for (int tap = 0; tap < 9; ++tap) {
        #pragma unroll
        for (int ks = 0; ks < 4; ++ks) {
            bf16x8 af[2], bfr[4];
            #pragma unroll
            for (int mt = 0; mt < 2; ++mt)
                af[mt] = *(const bf16x8*)(wtb + ((size_t)tap * 1024 + m0 + wave * 32 + mt * 16 + ln) * 128 + ks * 32 + quad * 8);
            #pragma unroll
            for (int nt = 0; nt < 4; ++nt) {
                bfr[nt] = *(const bf16x8*)&Y[(nt * 16 + ln + tap) * 136 + ks * 32 + quad * 8];
                int w = ((l0 + nt * 16 + ln) & 511) + tap - 4;
                bool ok = (w >= 0) && (w < 512);
                bfr[nt] = ok ? bfr[nt] : zv;
            }
            #pragma unroll
            for (int mt = 0; mt < 2; ++mt)
                #pragma unroll
                for (int nt = 0; nt < 4; ++nt)
                    acc[mt][nt] = __builtin_amdgcn_mfma_f32_16x16x32_bf16(af[mt], bfr[nt], acc[mt][nt], 0, 0, 0);
        }
    }
    __syncthreads();
    #pragma unroll
    for (int mt = 0; mt < 2; ++mt) {
        float4 cv = *(const float4*)(cvec + m0 + wave * 32 + mt * 16 + quad * 4);
        #pragma unroll
        for (int nt = 0; nt < 4; ++nt) {
            float z[4], o[4];
            #pragma unroll
            for (int r = 0; r < 4; ++r) {
                z[r] = acc[mt][nt][r] * kInvSqrt1152 * ((const float*)&cv)[r];
                float sig = 1.0f / (1.0f + __expf(-z[r]));
                o[r] = z[r] * sig * kInvSilu;
            }
            *(uint2*)&Sout[(nt * 16 + ln) * 136 + wave * 32 + mt * 16 + quad * 4] =
                pk4(o[0], o[1], o[2], o[3]);
        }
    }
    __syncthreads();
    #pragma unroll
    for (int i = 0; i < 4; ++i) {
        int c = t + 256 * i;
        int row = c >> 4, cc = c & 15;
        *(uint4*)(y2t + (size_t)(l0 + row) * 1024 + m0 + cc * 8) = *(uint4*)&Sout[row * 136 + cc * 8];
    }
}

// ---------------------------------------------------------------------------
__global__ void k_mpsum_t(const u16* __restrict__ a, const u16* __restrict__ b,
                          u16* __restrict__ out) {
    size_t base = ((size_t)blockIdx.x * 256 + threadIdx.x) * 8;
    uint4 av = *(const uint4*)(a + base);
    uint4 bv = *(const uint4*)(b + base);
    const u16* ap = (const u16*)&av;
    const u16* bp = (const u16*)&bv;
    u16 o[8];
    #pragma unroll
    for (int i = 0; i < 8; ++i) o[i] = f2bf((bf2f(ap[i]) + bf2f(bp[i])) * kInvSqrt2);
    *(uint4*)(out + base) = *(uint4*)o;
}

__global__ void k_pe_t(const u16* __restrict__ xs, const u16* __restrict__ pos,
                       u16* __restrict__ pe) {
    int idx = blockIdx.x * 256 + threadIdx.x;
    int l = idx >> 6, cq = idx & 63;
    size_t src = (size_t)l * 512 + cq * 8;
    uint4 xv = *(const uint4*)(xs + src);
    uint4 pv = *(const uint4*)(pos + src);
    const u16* xp = (const u16*)&xv;
    const u16* pp = (const u16*)&pv;
    u16 o[16];
    #pragma unroll
    for (int i = 0; i < 8; ++i) {
        o[2 * i] = xp[i];
        o[2 * i + 1] = f2bf(bf2f(xp[i]) * bf2f(pp[i]));
    }
    u16* dst = pe + (size_t)l * 1024 + cq * 16;
    *(uint4*)dst = *(uint4*)&o[0];
    *(uint4*)(dst + 8) = *(uint4*)&o[8];
}

// ---------------------------------------------------------------------------
__global__ void k_norm_qk2(const u16* __restrict__ qk, u16* __restrict__ q_t,
                           u16* __restrict__ k_t) {
    int wave = threadIdx.x >> 6, lane = threadIdx.x & 63;
    int l = blockIdx.x * 4 + wave;
    const u16* row = qk + (size_t)l * 1024 + lane * 16;
    uint4 a = *(const uint4*)row;
    uint4 b = *(const uint4*)(row + 8);
    const u16* vp = (const u16*)&a;
    const u16* wp = (const u16*)&b;
    float v[16];
    #pragma unroll
    for (int i = 0; i < 8; ++i) { v[i] = bf2f(vp[i]); v[8 + i] = bf2f(wp[i]); }
    float ss0 = 0.f, ss1 = 0.f;
    #pragma unroll
    for (int i = 0; i < 8; ++i) { ss0 += v[2 * i] * v[2 * i]; ss1 += v[2 * i + 1] * v[2 * i + 1]; }
    #pragma unroll
    for (int off = 1; off < 16; off <<= 1) {
        ss0 += __shfl_xor(ss0, off);
        ss1 += __shfl_xor(ss1, off);
    }
    float rn0 = kQScale / (kEps + sqrtf(ss0 * (1.0f / 128.0f)));
    float rn1 = 1.0f / (kEps + sqrtf(ss1 * (1.0f / 128.0f)));
    int h = lane >> 4;
    u16 qo[8], ko[8];
    #pragma unroll
    for (int i = 0; i < 8; ++i) {
        qo[i] = f2bf(v[2 * i] * rn0);
        ko[i] = f2bf(v[2 * i + 1] * rn1);
    }
    size_t dst = ((size_t)h * LDIM + l) * 128 + (lane & 15) * 8;
    *(uint4*)(q_t + dst) = *(uint4*)qo;
    *(uint4*)(k_t + dst) = *(uint4*)ko;
}

__global__ void k_norm_v2(u16* __restrict__ v_t) {
    int wave = threadIdx.x >> 6, lane = threadIdx.x & 63;
    int l = blockIdx.x * 4 + wave;
    u16* p = v_t + (size_t)l * 512 + lane * 8;
    uint4 a = *(const uint4*)p;
    const u16* vp = (const u16*)&a;
    float v[8], ss = 0.f;
    #pragma unroll
    for (int i = 0; i < 8; ++i) { v[i] = bf2f(vp[i]); ss += v[i] * v[i]; }
    #pragma unroll
    for (int off = 1; off < 16; off <<= 1) ss += __shfl_xor(ss, off);
    float rn = 1.0f / (kEps + sqrtf(ss * (1.0f / 128.0f)));
    u16 o[8];
    #pragma unroll
    for (int i = 0; i < 8; ++i) o[i] = f2bf(v[i] * rn);
    *(uint4*)p = *(uint4*)o;
}

// ---------------------------------------------------------------------------
// MFMA flash attention v3. TQ=256/block (4 waves x 64 q-rows), TK=64, K-split=2.
// Per-wave 64-row Q strip doubles MFMA per LDS byte vs v2. Grid = 256 blocks
// (1/CU); blockIdx&7 selects (h,sp) so the 32 blocks sharing a K/V slice land
// on one XCD (slice = 2 MB, fits 4 MiB XCD L2).
// P staged in two 32-j halves to keep LDS at 55 KB.
#define PSP 40   // Ps row pitch in u16 (32 j + 8 pad); 5 x 16B units => conflict-free
__launch_bounds__(256, 1)
__global__ void k_attn3(const u16* __restrict__ q_t, const u16* __restrict__ k_t,
                        const u16* __restrict__ vt2, u16* __restrict__ Opart,
                        float* __restrict__ lsumG) {
    __shared__ u16 Ks[64 * 136];    // [j][d]   (17 16B-units/row)
    __shared__ u16 Vs[128 * 72];    // [d][j]   (9 units/row)
    __shared__ u16 Ps[256 * PSP];   // [i][j-half]
    const int t = threadIdx.x;
    const int lane = t & 63, wave = t >> 6;
    const int quad = lane >> 4, ln = lane & 15;
    const int b = blockIdx.x;
    const int h = (b >> 1) & 3, sp = b & 1;
    const int i0 = (b >> 3) * 256;
    const int jb0 = sp * 4096, jend = jb0 + 4096;
    const u16* qg = q_t + (size_t)h * LDIM * 128;
    const u16* kg = k_t + (size_t)h * LDIM * 128;
    const u16* vg = vt2 + (size_t)h * 128 * LDIM;

    // Q fragments: rows i0 + wave*64 + mt*16 + ln, k = ks*32 + quad*8 + r
    bf16x8 qf[4][4];
    #pragma unroll
    for (int mt = 0; mt < 4; ++mt) {
        int row = i0 + wave * 64 + mt * 16 + ln;
        #pragma unroll
        for (int ks = 0; ks < 4; ++ks)
            qf[mt][ks] = *(const bf16x8*)(qg + (size_t)row * 128 + ks * 32 + quad * 8);
    }

    f32x4 o_acc[4][8] = {};
    float lsum[4] = {};

    // stage first K/V tile
    #pragma unroll
    for (int i = 0; i < 4; ++i) {
        int c = t + 256 * i;
        *(uint4*)&Ks[(c >> 4) * 136 + (c & 15) * 8] =
            *(const uint4*)(kg + (size_t)(jb0 + (c >> 4)) * 128 + (c & 15) * 8);
        *(uint4*)&Vs[(c >> 3) * 72 + (c & 7) * 8] =
            *(const uint4*)(vg + (size_t)(c >> 3) * LDIM + jb0 + (c & 7) * 8);
    }
    __syncthreads();

    const int istrip = wave * 64;

    for (int jb = jb0; jb < jend; jb += 64) {
        uint4 kx[4], vx[4];
        const bool pf = (jb + 64 < jend);
        if (pf) {
            #pragma unroll
            for (int i = 0; i < 4; ++i) {
                int c = t + 256 * i;
                kx[i] = *(const uint4*)(kg + (size_t)(jb + 64 + (c >> 4)) * 128 + (c & 15) * 8);
                vx[i] = *(const uint4*)(vg + (size_t)(c >> 3) * LDIM + jb + 64 + (c & 7) * 8);
            }
        }
        // two 32-j halves: S^T -> exp -> Ps strip -> PV  (all per-wave, no barrier)
        #pragma unroll
        for (int half = 0; half < 2; ++half) {
            #pragma unroll
            for (int jt = half * 2; jt < half * 2 + 2; ++jt) {
                f32x4 st[4] = {};
                #pragma unroll
                for (int ks = 0; ks < 4; ++ks) {
                    bf16x8 af = *(const bf16x8*)&Ks[(jt * 16 + ln) * 136 + ks * 32 + quad * 8];
                    #pragma unroll
                    for (int mt = 0; mt < 4; ++mt)
                        st[mt] = __builtin_amdgcn_mfma_f32_16x16x32_bf16(af, qf[mt][ks], st[mt], 0, 0, 0);
                }
                #pragma unroll
                for (int mt = 0; mt < 4; ++mt) {
                    float p0 = __expf(st[mt][0]);
                    float p1 = __expf(st[mt][1]);
                    float p2 = __expf(st[mt][2]);
                    float p3 = __expf(st[mt][3]);
                    lsum[mt] += p0 + p1 + p2 + p3;
                    *(uint2*)&Ps[(istrip + mt * 16 + ln) * PSP + (jt - half * 2) * 16 + quad * 4] =
                        pk4(p0, p1, p2, p3);
                }
            }
            // PV for this half: j = half*32 + quad*8 + r
            bf16x8 ap[4];
            #pragma unroll
            for (int mt = 0; mt < 4; ++mt)
                ap[mt] = *(const bf16x8*)&Ps[(istrip + mt * 16 + ln) * PSP + quad * 8];
            #pragma unroll
            for (int dt = 0; dt < 8; ++dt) {
                bf16x8 bv = *(const bf16x8*)&Vs[(dt * 16 + ln) * 72 + half * 32 + quad * 8];
                #pragma unroll
                for (int mt = 0; mt < 4; ++mt)
                    o_acc[mt][dt] = __builtin_amdgcn_mfma_f32_16x16x32_bf16(ap[mt], bv, o_acc[mt][dt], 0, 0, 0);
            }
        }
        __syncthreads();
        if (pf) {
            #pragma unroll
            for (int i = 0; i < 4; ++i) {
                int c = t + 256 * i;
                *(uint4*)&Ks[(c >> 4) * 136 + (c & 15) * 8] = kx[i];
                *(uint4*)&Vs[(c >> 3) * 72 + (c & 7) * 8] = vx[i];
            }
        }
        __syncthreads();
    }

    // row sums: reduce across the 4 quads holding each i (lanes ln, ln+16, +32, +48)
    #pragma unroll
    for (int mt = 0; mt < 4; ++mt) {
        float s = lsum[mt];
        s += __shfl_xor(s, 16);
        s += __shfl_xor(s, 32);
        if (quad == 0)
            lsumG[(size_t)(sp * 4 + h) * LDIM + i0 + istrip + mt * 16 + ln] = s;
    }
    // partial O: bf16 [sp][c=h*128+d][L]; lane writes 4 consecutive tokens
    u16* og = Opart + (size_t)sp * 512 * LDIM;
    #pragma unroll
    for (int mt = 0; mt < 4; ++mt)
        #pragma unroll
        for (int dt = 0; dt < 8; ++dt) {
            f32x4 o = o_acc[mt][dt];
            *(uint2*)(og + (size_t)(h * 128 + dt * 16 + ln) * LDIM + i0 + istrip + mt * 16 + quad * 4) =
                pk4(o[0], o[1], o[2], o[3]);
        }
}

// combine: out[c][l] = clip((xs + (O0+O1)/(l0+l1)) / sqrt(2))
__global__ void k_combine(const u16* __restrict__ Opart, const float* __restrict__ lsumG,
                          const float* __restrict__ xs_cl, float* __restrict__ out) {
    int idx = blockIdx.x * 256 + threadIdx.x;
    int c = idx >> 11;
    int lq = (idx & 2047) * 4;
    int h = c >> 7;
    uint2 a = *(const uint2*)(Opart + (size_t)c * LDIM + lq);
    uint2 b = *(const uint2*)(Opart + (size_t)(512 + c) * LDIM + lq);
    float4 s0 = *(const float4*)(lsumG + (size_t)h * LDIM + lq);
    float4 s1 = *(const float4*)(lsumG + (size_t)(4 + h) * LDIM + lq);
    float4 xv = *(const float4*)(xs_cl + (size_t)c * LDIM + lq);
    const u16* ap = (const u16*)&a;
    const u16* bp = (const u16*)&b;
    float ls[4] = {s0.x + s1.x, s0.y + s1.y, s0.z + s1.z, s0.w + s1.w};
    float xi[4] = {xv.x, xv.y, xv.z, xv.w};
    float4 o;
    float* op = (float*)&o;
    #pragma unroll
    for (int r = 0; r < 4; ++r) {
        float ov = (bf2f(ap[r]) + bf2f(bp[r])) / ls[r];
        float val = (xi[r] + ov) * kInvSqrt2;
        op[r] = fminf(fmaxf(val, -256.f), 256.f);
    }
    *(float4*)(out + (size_t)c * LDIM + lq) = o;
}

// ---------------------------------------------------------------------------
extern "C" void kernel_launch(void* const* d_in, const int* in_sizes, int n_in,
                              void* d_out, int out_size, void* d_ws, size_t ws_size,
                              hipStream_t stream) {
    const float* x      = (const float*)d_in[0];
    const float* emb    = (const float*)d_in[1];
    const float* pos    = (const float*)d_in[2];
    const float* eg     = (const float*)d_in[3];
    const float* w_res0 = (const float*)d_in[4];
    const float* w_depth= (const float*)d_in[5];
    const float* w_emb  = (const float*)d_in[6];
    const float* w_res1 = (const float*)d_in[7];
    const float* w_qk   = (const float*)d_in[8];
    const float* w_v    = (const float*)d_in[9];
    float* out = (float*)d_out;

    char* W = (char*)d_ws;
    const size_t MiB = 1024 * 1024;
    u16*   xt    = (u16*)(W);                      // 8 MiB  [8192][512]
    u16*   pos_t = (u16*)(W + 8 * MiB);            // 8 MiB; later vt2
    u16*   w0b   = (u16*)(W + 16 * MiB);
    u16*   w1b   = (u16*)(W + 17 * MiB);
    u16*   wqb   = (u16*)(W + 18 * MiB);
    u16*   wvb   = (u16*)(W + 20 * MiB);
    u16*   wtb   = (u16*)(W + 20 * MiB + 512 * 1024);
    float* cvec  = (float*)(W + 22 * MiB + 768 * 1024);
    float* rnv   = (float*)(W + 22 * MiB + 896 * 1024); // 32 KiB
    float* lsumG = (float*)(W + 23 * MiB);         // 256 KiB
    u16*   bufD  = (u16*)(W + 24 * MiB);           // 16 MiB: y1t -> qk_t -> xs_cl
    u16*   bufE  = (u16*)(W + 40 * MiB);           // 16 MiB: y2t -> pe_t -> v_t -> Opart
    u16*   k_t   = (u16*)(W + 56 * MiB);           // 8 MiB
    u16*   xs_t  = (u16*)(W + 64 * MiB);           // 8 MiB
    u16*   bufH  = (u16*)(W + 72 * MiB);           // 8 MiB: y3t -> q_t
    u16*   vt2   = pos_t;
    float* xs_cl = (float*)bufD;

    k_prep_w<<<2048, 256, 0, stream>>>(w_res0, w_res1, w_qk, w_v, w_depth,
                                       w0b, w1b, wqb, wvb, wtb);
    k_emb<<<256, 256, 0, stream>>>(w_emb, emb, eg, cvec);
    k_rn<<<128, 256, 0, stream>>>(x, rnv);
    k_tr2<<<dim3(128, 8), 256, 0, stream>>>(x, rnv, xt);
    k_tr2<<<dim3(128, 8), 256, 0, stream>>>(pos, nullptr, pos_t);
    // y1 = res0(xn): [L][1024]
    k_gemm_tm<<<dim3(64, 8), 256, 0, stream>>>(xt, w0b, bufD, 512, 1024, kInvSqrt512);
    // y2 = silu(gconv(y1)*c): [L][1024]
    k_gconv_tm<<<dim3(128, 8), 256, 0, stream>>>(bufD, wtb, cvec, bufE);
    // y3 = res1(y2): [L][512]
    k_gemm_tm<<<dim3(64, 4), 256, 0, stream>>>(bufE, w1b, bufH, 1024, 512, kInvSqrt1024);
    // xs = (xn + y3)/sqrt(2)
    k_mpsum_t<<<2048, 256, 0, stream>>>(xt, bufH, xs_t);
    // pe
    k_pe_t<<<2048, 256, 0, stream>>>(xs_t, pos_t, bufE);
    // qk = wqk(pe): [L][1024]
    k_gemm_tm<<<dim3(64, 8), 256, 0, stream>>>(bufE, wqb, bufD, 1024, 1024, kInvSqrt1024);
    // q/k norm + head-split
    k_norm_qk2<<<2048, 256, 0, stream>>>(bufD, bufH, k_t);
    // xs channel-major fp32 (for final combine)
    k_tr_b2x<<<1024, 256, 0, stream>>>(xs_t, xs_cl, 0);
    // v = wv(xs): [L][512]
    k_gemm_tm<<<dim3(64, 4), 256, 0, stream>>>(xs_t, wvb, bufE, 512, 512, kInvSqrt512);
    k_norm_v2<<<2048, 256, 0, stream>>>(bufE);
    // v -> [512][L]
    k_tr_b2x<<<1024, 256, 0, stream>>>(bufE, vt2, 1);
    // attention partials (K-split 2, XCD-clustered)
    k_attn3<<<256, 256, 0, stream>>>(bufH, k_t, vt2, bufE, lsumG);
    // combine + residual + clip
    k_combine<<<4096, 256, 0, stream>>>(bufE, lsumG, xs_cl, out);
}